// Round 1
// baseline (8443.908 us; speedup 1.0000x reference)
//
#include <hip/hip_runtime.h>

// CD_BP_Net: belief-propagation community detection on MI355X.
// Layout decisions:
//  - One thread per UNDIRECTED edge pair (t, t+Eh): rev-edge is the pair
//    partner, weights symmetric -> in-place L update, shared expm1_bw.
//  - psi never materialized: fused softmax(msg)->log1p(psi*em)->scatter S.
//  - S double-buffered (1.6MB each, L2-resident); L single buffer in-place.
//  - Scalars (two_m, hsum, link, comm_deg) accumulated in double via
//    wave-reduce + one atomic per wave.

#define NBLK 256
#define QD 4

__device__ __forceinline__ float wave_red(float v) {
#pragma unroll
  for (int o = 32; o > 0; o >>= 1) v += __shfl_down(v, o, 64);
  return v;
}

__device__ __forceinline__ float4 softmax4(float a, float b, float c, float d) {
  float mx = fmaxf(fmaxf(a, b), fmaxf(c, d));
  float e0 = expf(a - mx), e1 = expf(b - mx), e2 = expf(c - mx), e3 = expf(d - mx);
  float inv = 1.f / (e0 + e1 + e2 + e3);
  return make_float4(e0 * inv, e1 * inv, e2 * inv, e3 * inv);
}

// Setup: two_m, weighted degree, psi0 (normalized msg_init), em=expm1(beta*w),
// L0 = log1p(psi0*em), S0 = segment_sum(L0 by dst).
__global__ void setup_edges(const int* __restrict__ ei, const float* __restrict__ w,
                            const float* __restrict__ msg, const float* __restrict__ beta_p,
                            float* __restrict__ L, float* __restrict__ S0,
                            float* __restrict__ em_buf, float* __restrict__ deg,
                            double* __restrict__ two_m, int E, int Eh) {
  int t = blockIdx.x * blockDim.x + threadIdx.x;
  float tw = 0.f;
  if (t < Eh) {
    float beta = beta_p[0];
    int s1 = ei[t];        // src of forward edge
    int d1 = ei[E + t];    // dst of forward edge
    float wv = w[t];       // == w[t+Eh]
    tw = 2.f * wv;
    atomicAdd(&deg[s1], wv);
    atomicAdd(&deg[d1], wv);
    float em = expm1f(beta * wv);
    em_buf[t] = em;
    float4 m1 = *reinterpret_cast<const float4*>(&msg[(size_t)t * QD]);
    float4 m2 = *reinterpret_cast<const float4*>(&msg[((size_t)t + Eh) * QD]);
    float i1 = 1.f / (m1.x + m1.y + m1.z + m1.w);
    float i2 = 1.f / (m2.x + m2.y + m2.z + m2.w);
    float4 L1 = make_float4(log1pf(m1.x * i1 * em), log1pf(m1.y * i1 * em),
                            log1pf(m1.z * i1 * em), log1pf(m1.w * i1 * em));
    float4 L2 = make_float4(log1pf(m2.x * i2 * em), log1pf(m2.y * i2 * em),
                            log1pf(m2.z * i2 * em), log1pf(m2.w * i2 * em));
    *reinterpret_cast<float4*>(&L[(size_t)t * QD]) = L1;
    *reinterpret_cast<float4*>(&L[((size_t)t + Eh) * QD]) = L2;
    atomicAdd(&S0[(size_t)d1 * QD + 0], L1.x);
    atomicAdd(&S0[(size_t)d1 * QD + 1], L1.y);
    atomicAdd(&S0[(size_t)d1 * QD + 2], L1.z);
    atomicAdd(&S0[(size_t)d1 * QD + 3], L1.w);
    atomicAdd(&S0[(size_t)s1 * QD + 0], L2.x);
    atomicAdd(&S0[(size_t)s1 * QD + 1], L2.y);
    atomicAdd(&S0[(size_t)s1 * QD + 2], L2.z);
    atomicAdd(&S0[(size_t)s1 * QD + 3], L2.w);
  }
  tw = wave_red(tw);
  if ((threadIdx.x & 63) == 0 && tw != 0.f) atomicAdd(two_m, (double)tw);
}

// Node step: marg = softmax(h_prev + S_cur); hsum_new += deg*marg.
// h_prev[k] = -(beta/two_m) * hsum_prev[k] (hsum_prev zeroed => h=0 at iter 1).
__global__ void node_step(const float* __restrict__ S_cur,
                          const double* __restrict__ hsum_prev,
                          double* __restrict__ hsum_new,
                          const float* __restrict__ deg,
                          const float* __restrict__ beta_p,
                          const double* __restrict__ two_m, int N) {
  int n = blockIdx.x * blockDim.x + threadIdx.x;
  float scale = -beta_p[0] / (float)two_m[0];
  float h0 = scale * (float)hsum_prev[0];
  float h1 = scale * (float)hsum_prev[1];
  float h2 = scale * (float)hsum_prev[2];
  float h3 = scale * (float)hsum_prev[3];
  float a0 = 0.f, a1 = 0.f, a2 = 0.f, a3 = 0.f;
  if (n < N) {
    float4 S = *reinterpret_cast<const float4*>(&S_cur[(size_t)n * QD]);
    float4 p = softmax4(h0 + S.x, h1 + S.y, h2 + S.z, h3 + S.w);
    float d = deg[n];
    a0 = d * p.x; a1 = d * p.y; a2 = d * p.z; a3 = d * p.w;
  }
  a0 = wave_red(a0); a1 = wave_red(a1); a2 = wave_red(a2); a3 = wave_red(a3);
  if ((threadIdx.x & 63) == 0) {
    atomicAdd(&hsum_new[0], (double)a0);
    atomicAdd(&hsum_new[1], (double)a1);
    atomicAdd(&hsum_new[2], (double)a2);
    atomicAdd(&hsum_new[3], (double)a3);
  }
}

// Edge step (fused cavity update): for both directed edges of pair t:
//   msg = h_new + S_cur[src] - L[rev]; psi = softmax(msg);
//   L_new = log1p(psi*em) written IN PLACE; S_new[dst] += L_new.
__global__ void edge_step(const int* __restrict__ ei, const float* __restrict__ em_buf,
                          const float* __restrict__ S_cur, float* __restrict__ S_new,
                          float* __restrict__ L, const double* __restrict__ hsum,
                          const float* __restrict__ beta_p,
                          const double* __restrict__ two_m, int E, int Eh) {
  int t = blockIdx.x * blockDim.x + threadIdx.x;
  if (t >= Eh) return;
  float scale = -beta_p[0] / (float)two_m[0];
  float h0 = scale * (float)hsum[0];
  float h1 = scale * (float)hsum[1];
  float h2 = scale * (float)hsum[2];
  float h3 = scale * (float)hsum[3];
  int s1 = ei[t];
  int d1 = ei[E + t];
  float em = em_buf[t];
  float4 L1 = *reinterpret_cast<const float4*>(&L[(size_t)t * QD]);
  float4 L2 = *reinterpret_cast<const float4*>(&L[((size_t)t + Eh) * QD]);
  float4 Ss = *reinterpret_cast<const float4*>(&S_cur[(size_t)s1 * QD]);
  float4 Sd = *reinterpret_cast<const float4*>(&S_cur[(size_t)d1 * QD]);
  // forward edge t: src=s1, rev=t+Eh (whose L is L2)
  float4 p1 = softmax4(h0 + Ss.x - L2.x, h1 + Ss.y - L2.y,
                       h2 + Ss.z - L2.z, h3 + Ss.w - L2.w);
  // reverse edge t+Eh: src=d1, rev=t (L1)
  float4 p2 = softmax4(h0 + Sd.x - L1.x, h1 + Sd.y - L1.y,
                       h2 + Sd.z - L1.z, h3 + Sd.w - L1.w);
  float4 n1 = make_float4(log1pf(p1.x * em), log1pf(p1.y * em),
                          log1pf(p1.z * em), log1pf(p1.w * em));
  float4 n2 = make_float4(log1pf(p2.x * em), log1pf(p2.y * em),
                          log1pf(p2.z * em), log1pf(p2.w * em));
  *reinterpret_cast<float4*>(&L[(size_t)t * QD]) = n1;
  *reinterpret_cast<float4*>(&L[((size_t)t + Eh) * QD]) = n2;
  atomicAdd(&S_new[(size_t)d1 * QD + 0], n1.x);
  atomicAdd(&S_new[(size_t)d1 * QD + 1], n1.y);
  atomicAdd(&S_new[(size_t)d1 * QD + 2], n1.z);
  atomicAdd(&S_new[(size_t)d1 * QD + 3], n1.w);
  atomicAdd(&S_new[(size_t)s1 * QD + 0], n2.x);
  atomicAdd(&S_new[(size_t)s1 * QD + 1], n2.y);
  atomicAdd(&S_new[(size_t)s1 * QD + 2], n2.z);
  atomicAdd(&S_new[(size_t)s1 * QD + 3], n2.w);
}

// Final marginals: s = softmax(h + S_final) -> d_out; comm_raw += deg*s.
__global__ void node_final(const float* __restrict__ S_cur,
                           const double* __restrict__ hsum,
                           const float* __restrict__ deg,
                           const float* __restrict__ beta_p,
                           const double* __restrict__ two_m,
                           float* __restrict__ out_s,
                           double* __restrict__ comm_raw, int N) {
  int n = blockIdx.x * blockDim.x + threadIdx.x;
  float scale = -beta_p[0] / (float)two_m[0];
  float h0 = scale * (float)hsum[0];
  float h1 = scale * (float)hsum[1];
  float h2 = scale * (float)hsum[2];
  float h3 = scale * (float)hsum[3];
  float a0 = 0.f, a1 = 0.f, a2 = 0.f, a3 = 0.f;
  if (n < N) {
    float4 S = *reinterpret_cast<const float4*>(&S_cur[(size_t)n * QD]);
    float4 p = softmax4(h0 + S.x, h1 + S.y, h2 + S.z, h3 + S.w);
    *reinterpret_cast<float4*>(&out_s[(size_t)n * QD]) = p;
    float d = deg[n];
    a0 = d * p.x; a1 = d * p.y; a2 = d * p.z; a3 = d * p.w;
  }
  a0 = wave_red(a0); a1 = wave_red(a1); a2 = wave_red(a2); a3 = wave_red(a3);
  if ((threadIdx.x & 63) == 0) {
    atomicAdd(&comm_raw[0], (double)a0);
    atomicAdd(&comm_raw[1], (double)a1);
    atomicAdd(&comm_raw[2], (double)a2);
    atomicAdd(&comm_raw[3], (double)a3);
  }
}

// link_raw = sum over directed edges of w*<s_src, s_dst> = 2*w_und*dot per pair.
__global__ void edge_final(const int* __restrict__ ei, const float* __restrict__ w,
                           const float* __restrict__ out_s,
                           double* __restrict__ link_raw, int E, int Eh) {
  int t = blockIdx.x * blockDim.x + threadIdx.x;
  float c = 0.f;
  if (t < Eh) {
    int s1 = ei[t];
    int d1 = ei[E + t];
    float4 a = *reinterpret_cast<const float4*>(&out_s[(size_t)s1 * QD]);
    float4 b = *reinterpret_cast<const float4*>(&out_s[(size_t)d1 * QD]);
    float dot = a.x * b.x + a.y * b.y + a.z * b.z + a.w * b.w;
    c = 2.f * w[t] * dot;
  }
  c = wave_red(c);
  if ((threadIdx.x & 63) == 0 && c != 0.f) atomicAdd(link_raw, (double)c);
}

__global__ void finalize(const double* __restrict__ scal, float* __restrict__ out_q) {
  // scal: [0]=two_m, [1]=link_raw, [2..5]=comm_raw
  double tm = scal[0];
  double link = scal[1] / tm;
  double acc = 0.0;
#pragma unroll
  for (int k = 0; k < QD; ++k) {
    double c = scal[2 + k] / tm;
    acc += c * c;
  }
  out_q[0] = (float)(link - acc);
}

extern "C" void kernel_launch(void* const* d_in, const int* in_sizes, int n_in,
                              void* d_out, int out_size, void* d_ws, size_t ws_size,
                              hipStream_t stream) {
  const int* ei = (const int*)d_in[0];        // [2, E] row-major int32
  const float* w = (const float*)d_in[1];     // [E]
  const float* msg = (const float*)d_in[2];   // [E, 4]
  const float* beta_p = (const float*)d_in[3];// scalar

  const int E = in_sizes[1];
  const int Eh = E / 2;
  const int N = (out_size - 1) / QD;          // out = s[N,4] ++ q_mod

  // ws layout
  char* p = (char*)d_ws;
  double* scal = (double*)p; // [0]=two_m [1]=link [2..5]=comm [6..9]=hsum0 [10..13]=hsum1
  size_t off = 128;
  float* deg = (float*)(p + off); off += (size_t)N * 4;
  off = (off + 15) & ~(size_t)15;
  float* S0 = (float*)(p + off); off += (size_t)N * QD * 4;
  float* S1 = (float*)(p + off); off += (size_t)N * QD * 4;
  float* em = (float*)(p + off); off += (size_t)Eh * 4;
  off = (off + 15) & ~(size_t)15;
  float* L = (float*)(p + off); off += (size_t)E * QD * 4;
  (void)ws_size;

  double* hs[2] = {scal + 6, scal + 10};
  float* S[2] = {S0, S1};
  const int gE = (Eh + NBLK - 1) / NBLK;
  const int gN = (N + NBLK - 1) / NBLK;

  hipMemsetAsync(scal, 0, 128, stream);
  hipMemsetAsync(deg, 0, (size_t)N * 4, stream);
  hipMemsetAsync(S0, 0, (size_t)N * QD * 4, stream);
  setup_edges<<<gE, NBLK, 0, stream>>>(ei, w, msg, beta_p, L, S0, em, deg, scal, E, Eh);

  for (int i = 1; i <= 10; ++i) {
    int cur = (i - 1) & 1, nw = i & 1;
    hipMemsetAsync(hs[nw], 0, 4 * sizeof(double), stream);
    hipMemsetAsync(S[nw], 0, (size_t)N * QD * 4, stream);
    node_step<<<gN, NBLK, 0, stream>>>(S[cur], hs[cur], hs[nw], deg, beta_p, scal, N);
    edge_step<<<gE, NBLK, 0, stream>>>(ei, em, S[cur], S[nw], L, hs[nw], beta_p, scal, E, Eh);
  }

  // After 10 iters: S_final = S[0], hsum_final = hs[0].
  float* out_s = (float*)d_out;
  node_final<<<gN, NBLK, 0, stream>>>(S[0], hs[0], deg, beta_p, scal, out_s, scal + 2, N);
  edge_final<<<gE, NBLK, 0, stream>>>(ei, w, out_s, scal + 1, E, Eh);
  finalize<<<1, 1, 0, stream>>>(scal, out_s + (size_t)N * QD);
}

// Round 3
// 4538.641 us; speedup vs baseline: 1.8604x; 1.8604x over previous
//
#include <hip/hip_runtime.h>

// CD_BP_Net: belief-propagation community detection on MI355X.
// R2 (resubmit; R2 bench never ran): atomic-free iterations via CSR gather.
//  - One-time CSR build (hist+rank -> scan -> scatter); only 3.2M int atomics.
//  - node_step: gather L[inc[k]] per node (4 lanes/node), sum -> S, softmax,
//    hsum via wave-reduce + one double atomic per wave.
//  - edge_step: one thread per undirected pair owns edges (t, t+Eh); reads
//    S[src],S[dst],L pair; writes L in place. Zero atomics.
//  - h accumulators: 11 slots in scal block, zeroed once (no per-iter memsets).

#define NBLK 256
#define QD 4

__device__ __forceinline__ float wave_red(float v) {
#pragma unroll
  for (int o = 32; o > 0; o >>= 1) v += __shfl_down(v, o, 64);
  return v;
}

__device__ __forceinline__ float4 softmax4(float a, float b, float c, float d) {
  float mx = fmaxf(fmaxf(a, b), fmaxf(c, d));
  float e0 = expf(a - mx), e1 = expf(b - mx), e2 = expf(c - mx), e3 = expf(d - mx);
  float inv = 1.f / (e0 + e1 + e2 + e3);
  return make_float4(e0 * inv, e1 * inv, e2 * inv, e3 * inv);
}

// ---- CSR build ----------------------------------------------------------
__global__ void hist_rank(const int* __restrict__ ei, int* __restrict__ cnt,
                          int* __restrict__ rank, int E) {
  int e = blockIdx.x * blockDim.x + threadIdx.x;
  if (e >= E) return;
  int d = ei[E + e];
  rank[e] = atomicAdd(&cnt[d], 1);
}

// exclusive scan of cnt[N] -> rowStart[N]; 1024 elems/block
__global__ void scanA(const int* __restrict__ cnt, int* __restrict__ out,
                      int* __restrict__ bsum, int N) {
  __shared__ int lds[256];
  int base = blockIdx.x * 1024 + threadIdx.x * 4;
  int v0 = (base + 0 < N) ? cnt[base + 0] : 0;
  int v1 = (base + 1 < N) ? cnt[base + 1] : 0;
  int v2 = (base + 2 < N) ? cnt[base + 2] : 0;
  int v3 = (base + 3 < N) ? cnt[base + 3] : 0;
  lds[threadIdx.x] = v0 + v1 + v2 + v3;
  __syncthreads();
  for (int off = 1; off < 256; off <<= 1) {
    int x = (threadIdx.x >= off) ? lds[threadIdx.x - off] : 0;
    __syncthreads();
    if (threadIdx.x >= off) lds[threadIdx.x] += x;
    __syncthreads();
  }
  int excl = (threadIdx.x == 0) ? 0 : lds[threadIdx.x - 1];
  if (threadIdx.x == 255) bsum[blockIdx.x] = lds[255];
  if (base + 0 < N) out[base + 0] = excl;
  if (base + 1 < N) out[base + 1] = excl + v0;
  if (base + 2 < N) out[base + 2] = excl + v0 + v1;
  if (base + 3 < N) out[base + 3] = excl + v0 + v1 + v2;
}

__global__ void scanB(int* __restrict__ bsum, int NB) {
  __shared__ int lds[256];
  int v = (threadIdx.x < NB) ? bsum[threadIdx.x] : 0;
  lds[threadIdx.x] = v;
  __syncthreads();
  for (int off = 1; off < 256; off <<= 1) {
    int x = (threadIdx.x >= off) ? lds[threadIdx.x - off] : 0;
    __syncthreads();
    if (threadIdx.x >= off) lds[threadIdx.x] += x;
    __syncthreads();
  }
  int excl = (threadIdx.x == 0) ? 0 : lds[threadIdx.x - 1];
  if (threadIdx.x < NB) bsum[threadIdx.x] = excl;
}

__global__ void scanC(int* __restrict__ rowStart, const int* __restrict__ bsum,
                      int N, int E) {
  int i = blockIdx.x * blockDim.x + threadIdx.x;
  if (i < N) rowStart[i] += bsum[i >> 10];
  if (i == 0) rowStart[N] = E;
}

__global__ void scatter_inc(const int* __restrict__ ei, const int* __restrict__ rowStart,
                            const int* __restrict__ rank, int* __restrict__ inc, int E) {
  int e = blockIdx.x * blockDim.x + threadIdx.x;
  if (e >= E) return;
  int d = ei[E + e];
  inc[rowStart[d] + rank[e]] = e;
}

// ---- per-pair setup: em, L0, two_m -------------------------------------
__global__ void setup_pairs(const float* __restrict__ w, const float* __restrict__ msg,
                            const float* __restrict__ beta_p, float* __restrict__ L,
                            float* __restrict__ em_buf, double* __restrict__ two_m,
                            int Eh) {
  int t = blockIdx.x * blockDim.x + threadIdx.x;
  float tw = 0.f;
  if (t < Eh) {
    float beta = beta_p[0];
    float wv = w[t];  // == w[t+Eh]
    tw = 2.f * wv;
    float em = expm1f(beta * wv);
    em_buf[t] = em;
    float4 m1 = *reinterpret_cast<const float4*>(&msg[(size_t)t * QD]);
    float4 m2 = *reinterpret_cast<const float4*>(&msg[((size_t)t + Eh) * QD]);
    float i1 = 1.f / (m1.x + m1.y + m1.z + m1.w);
    float i2 = 1.f / (m2.x + m2.y + m2.z + m2.w);
    float4 L1 = make_float4(log1pf(m1.x * i1 * em), log1pf(m1.y * i1 * em),
                            log1pf(m1.z * i1 * em), log1pf(m1.w * i1 * em));
    float4 L2 = make_float4(log1pf(m2.x * i2 * em), log1pf(m2.y * i2 * em),
                            log1pf(m2.z * i2 * em), log1pf(m2.w * i2 * em));
    *reinterpret_cast<float4*>(&L[(size_t)t * QD]) = L1;
    *reinterpret_cast<float4*>(&L[((size_t)t + Eh) * QD]) = L2;
  }
  tw = wave_red(tw);
  if ((threadIdx.x & 63) == 0 && tw != 0.f) atomicAdd(two_m, (double)tw);
}

// deg[n] = sum of w over incident edges (4 lanes per node)
__global__ void node_deg(const int* __restrict__ rowStart, const int* __restrict__ inc,
                         const float* __restrict__ w, float* __restrict__ deg, int N) {
  int gid = blockIdx.x * blockDim.x + threadIdx.x;
  int n = gid >> 2, sub = gid & 3;
  if (n >= N) return;
  int s = rowStart[n], e = rowStart[n + 1];
  float a = 0.f;
  for (int k = s + sub; k < e; k += 4) a += w[inc[k]];
  a += __shfl_xor(a, 1, 64);
  a += __shfl_xor(a, 2, 64);
  if (sub == 0) deg[n] = a;
}

// S[n] = sum L[inc]; marg = softmax(h_prev + S); hsum_new += deg*marg
__global__ void node_step(const int* __restrict__ rowStart, const int* __restrict__ inc,
                          const float* __restrict__ L, const float* __restrict__ deg,
                          const double* __restrict__ hsum_prev, double* __restrict__ hsum_new,
                          const float* __restrict__ beta_p, const double* __restrict__ two_m,
                          float* __restrict__ S, int N) {
  int gid = blockIdx.x * blockDim.x + threadIdx.x;
  int n = gid >> 2, sub = gid & 3;
  float scale = -beta_p[0] / (float)two_m[0];
  float h0 = scale * (float)hsum_prev[0];
  float h1 = scale * (float)hsum_prev[1];
  float h2 = scale * (float)hsum_prev[2];
  float h3 = scale * (float)hsum_prev[3];
  float a0 = 0.f, a1 = 0.f, a2 = 0.f, a3 = 0.f;
  if (n < N) {
    int s = rowStart[n], e = rowStart[n + 1];
    float x0 = 0.f, x1 = 0.f, x2 = 0.f, x3 = 0.f;
    for (int k = s + sub; k < e; k += 4) {
      int eid = inc[k];
      float4 Lv = *reinterpret_cast<const float4*>(&L[(size_t)eid * QD]);
      x0 += Lv.x; x1 += Lv.y; x2 += Lv.z; x3 += Lv.w;
    }
#pragma unroll
    for (int m = 1; m <= 2; m <<= 1) {
      x0 += __shfl_xor(x0, m, 64);
      x1 += __shfl_xor(x1, m, 64);
      x2 += __shfl_xor(x2, m, 64);
      x3 += __shfl_xor(x3, m, 64);
    }
    if (sub == 0) {
      *reinterpret_cast<float4*>(&S[(size_t)n * QD]) = make_float4(x0, x1, x2, x3);
      float4 p = softmax4(h0 + x0, h1 + x1, h2 + x2, h3 + x3);
      float d = deg[n];
      a0 = d * p.x; a1 = d * p.y; a2 = d * p.z; a3 = d * p.w;
    }
  }
  a0 = wave_red(a0); a1 = wave_red(a1); a2 = wave_red(a2); a3 = wave_red(a3);
  if ((threadIdx.x & 63) == 0) {
    atomicAdd(&hsum_new[0], (double)a0);
    atomicAdd(&hsum_new[1], (double)a1);
    atomicAdd(&hsum_new[2], (double)a2);
    atomicAdd(&hsum_new[3], (double)a3);
  }
}

// cavity update, paired & in-place, zero atomics
__global__ void edge_step(const int* __restrict__ ei, const float* __restrict__ em_buf,
                          const float* __restrict__ S, float* __restrict__ L,
                          const double* __restrict__ hsum, const float* __restrict__ beta_p,
                          const double* __restrict__ two_m, int E, int Eh) {
  int t = blockIdx.x * blockDim.x + threadIdx.x;
  if (t >= Eh) return;
  float scale = -beta_p[0] / (float)two_m[0];
  float h0 = scale * (float)hsum[0];
  float h1 = scale * (float)hsum[1];
  float h2 = scale * (float)hsum[2];
  float h3 = scale * (float)hsum[3];
  int s1 = ei[t];
  int d1 = ei[E + t];
  float em = em_buf[t];
  float4 L1 = *reinterpret_cast<const float4*>(&L[(size_t)t * QD]);
  float4 L2 = *reinterpret_cast<const float4*>(&L[((size_t)t + Eh) * QD]);
  float4 Ss = *reinterpret_cast<const float4*>(&S[(size_t)s1 * QD]);
  float4 Sd = *reinterpret_cast<const float4*>(&S[(size_t)d1 * QD]);
  float4 p1 = softmax4(h0 + Ss.x - L2.x, h1 + Ss.y - L2.y,
                       h2 + Ss.z - L2.z, h3 + Ss.w - L2.w);
  float4 p2 = softmax4(h0 + Sd.x - L1.x, h1 + Sd.y - L1.y,
                       h2 + Sd.z - L1.z, h3 + Sd.w - L1.w);
  float4 n1 = make_float4(log1pf(p1.x * em), log1pf(p1.y * em),
                          log1pf(p1.z * em), log1pf(p1.w * em));
  float4 n2 = make_float4(log1pf(p2.x * em), log1pf(p2.y * em),
                          log1pf(p2.z * em), log1pf(p2.w * em));
  *reinterpret_cast<float4*>(&L[(size_t)t * QD]) = n1;
  *reinterpret_cast<float4*>(&L[((size_t)t + Eh) * QD]) = n2;
}

// final marginals: gather S, s = softmax(h + S) -> out; comm_raw += deg*s
__global__ void node_final(const int* __restrict__ rowStart, const int* __restrict__ inc,
                           const float* __restrict__ L, const float* __restrict__ deg,
                           const double* __restrict__ hsum, const float* __restrict__ beta_p,
                           const double* __restrict__ two_m, float* __restrict__ out_s,
                           double* __restrict__ comm_raw, int N) {
  int gid = blockIdx.x * blockDim.x + threadIdx.x;
  int n = gid >> 2, sub = gid & 3;
  float scale = -beta_p[0] / (float)two_m[0];
  float h0 = scale * (float)hsum[0];
  float h1 = scale * (float)hsum[1];
  float h2 = scale * (float)hsum[2];
  float h3 = scale * (float)hsum[3];
  float a0 = 0.f, a1 = 0.f, a2 = 0.f, a3 = 0.f;
  if (n < N) {
    int s = rowStart[n], e = rowStart[n + 1];
    float x0 = 0.f, x1 = 0.f, x2 = 0.f, x3 = 0.f;
    for (int k = s + sub; k < e; k += 4) {
      int eid = inc[k];
      float4 Lv = *reinterpret_cast<const float4*>(&L[(size_t)eid * QD]);
      x0 += Lv.x; x1 += Lv.y; x2 += Lv.z; x3 += Lv.w;
    }
#pragma unroll
    for (int m = 1; m <= 2; m <<= 1) {
      x0 += __shfl_xor(x0, m, 64);
      x1 += __shfl_xor(x1, m, 64);
      x2 += __shfl_xor(x2, m, 64);
      x3 += __shfl_xor(x3, m, 64);
    }
    if (sub == 0) {
      float4 p = softmax4(h0 + x0, h1 + x1, h2 + x2, h3 + x3);
      *reinterpret_cast<float4*>(&out_s[(size_t)n * QD]) = p;
      float d = deg[n];
      a0 = d * p.x; a1 = d * p.y; a2 = d * p.z; a3 = d * p.w;
    }
  }
  a0 = wave_red(a0); a1 = wave_red(a1); a2 = wave_red(a2); a3 = wave_red(a3);
  if ((threadIdx.x & 63) == 0) {
    atomicAdd(&comm_raw[0], (double)a0);
    atomicAdd(&comm_raw[1], (double)a1);
    atomicAdd(&comm_raw[2], (double)a2);
    atomicAdd(&comm_raw[3], (double)a3);
  }
}

__global__ void edge_final(const int* __restrict__ ei, const float* __restrict__ w,
                           const float* __restrict__ out_s,
                           double* __restrict__ link_raw, int E, int Eh) {
  int t = blockIdx.x * blockDim.x + threadIdx.x;
  float c = 0.f;
  if (t < Eh) {
    int s1 = ei[t];
    int d1 = ei[E + t];
    float4 a = *reinterpret_cast<const float4*>(&out_s[(size_t)s1 * QD]);
    float4 b = *reinterpret_cast<const float4*>(&out_s[(size_t)d1 * QD]);
    float dot = a.x * b.x + a.y * b.y + a.z * b.z + a.w * b.w;
    c = 2.f * w[t] * dot;
  }
  c = wave_red(c);
  if ((threadIdx.x & 63) == 0 && c != 0.f) atomicAdd(link_raw, (double)c);
}

__global__ void finalize(const double* __restrict__ scal, float* __restrict__ out_q) {
  double tm = scal[0];
  double link = scal[1] / tm;
  double acc = 0.0;
#pragma unroll
  for (int k = 0; k < QD; ++k) {
    double c = scal[2 + k] / tm;
    acc += c * c;
  }
  out_q[0] = (float)(link - acc);
}

extern "C" void kernel_launch(void* const* d_in, const int* in_sizes, int n_in,
                              void* d_out, int out_size, void* d_ws, size_t ws_size,
                              hipStream_t stream) {
  const int* ei = (const int*)d_in[0];         // [2,E] int32
  const float* w = (const float*)d_in[1];      // [E]
  const float* msg = (const float*)d_in[2];    // [E,4]
  const float* beta_p = (const float*)d_in[3]; // scalar

  const int E = in_sizes[1];
  const int Eh = E / 2;
  const int N = (out_size - 1) / QD;

  // ws layout:
  //   scal: [0]=two_m [1]=link [2..5]=comm [6+4*i .. 9+4*i]=hsum iter i (i=0..10)
  char* p = (char*)d_ws;
  double* scal = (double*)p;
  size_t off = 512;
  int* cnt = (int*)(p + off); off += (size_t)N * 4;
  int* rowStart = (int*)(p + off); off += (size_t)(N + 1) * 4;
  off = (off + 127) & ~(size_t)127;
  int* bsum = (int*)(p + off); off += 1024;
  int* inc = (int*)(p + off); off += (size_t)E * 4;
  float* deg = (float*)(p + off); off += (size_t)N * 4;
  off = (off + 15) & ~(size_t)15;
  float* S = (float*)(p + off); off += (size_t)N * QD * 4;
  float* em = (float*)(p + off); off += (size_t)Eh * 4;
  off = (off + 15) & ~(size_t)15;
  float* L = (float*)(p + off); off += (size_t)E * QD * 4;
  int* rank = (int*)L;  // alias: rank dead before L is first written
  (void)ws_size;

  double* hs = scal + 6;  // hs + 4*i for iteration i's field accumulator
  const int gEdir = (E + NBLK - 1) / NBLK;
  const int gE = (Eh + NBLK - 1) / NBLK;
  const int gN4 = (4 * N + NBLK - 1) / NBLK;
  const int NBscan = (N + 1023) / 1024;

  hipMemsetAsync(scal, 0, 512, stream);
  hipMemsetAsync(cnt, 0, (size_t)N * 4, stream);

  hist_rank<<<gEdir, NBLK, 0, stream>>>(ei, cnt, rank, E);
  scanA<<<NBscan, 256, 0, stream>>>(cnt, rowStart, bsum, N);
  scanB<<<1, 256, 0, stream>>>(bsum, NBscan);
  scanC<<<(N + NBLK) / NBLK, NBLK, 0, stream>>>(rowStart, bsum, N, E);
  scatter_inc<<<gEdir, NBLK, 0, stream>>>(ei, rowStart, rank, inc, E);

  setup_pairs<<<gE, NBLK, 0, stream>>>(w, msg, beta_p, L, em, scal, Eh);
  node_deg<<<gN4, NBLK, 0, stream>>>(rowStart, inc, w, deg, N);

  for (int i = 1; i <= 10; ++i) {
    node_step<<<gN4, NBLK, 0, stream>>>(rowStart, inc, L, deg, hs + 4 * (i - 1),
                                        hs + 4 * i, beta_p, scal, S, N);
    edge_step<<<gE, NBLK, 0, stream>>>(ei, em, S, L, hs + 4 * i, beta_p, scal, E, Eh);
  }

  float* out_s = (float*)d_out;
  node_final<<<gN4, NBLK, 0, stream>>>(rowStart, inc, L, deg, hs + 40, beta_p, scal,
                                       out_s, scal + 2, N);
  edge_final<<<gE, NBLK, 0, stream>>>(ei, w, out_s, scal + 1, E, Eh);
  finalize<<<1, 1, 0, stream>>>(scal, out_s + (size_t)N * QD);
}

// Round 5
// 2812.715 us; speedup vs baseline: 3.0020x; 1.6136x over previous
//
#include <hip/hip_runtime.h>

// CD_BP_Net: belief-propagation community detection on MI355X.
// R4 (resubmit; bench never ran): replace dependency-serialized CSR
// loop-gather (9 G req/s) with lane-per-slot gather + in-wave segmented
// reduction (max MLP):
//  - gatherL: one lane per CSR slot, ONE independent random L load each,
//    segmented shfl-scan by nodeOf[k], one atomicAdd per segment end -> S.
//  - node_post: per-node softmax/hsum from S (1.6MB, L2-resident).
//  - edge_step unchanged: paired in-place cavity update, zero atomics.
//  - Fallback to R3 loop-gather node_step if ws_size < needed (nodeOf +12.8MB).

#define NBLK 256
#define QD 4

__device__ __forceinline__ float wave_red(float v) {
#pragma unroll
  for (int o = 32; o > 0; o >>= 1) v += __shfl_down(v, o, 64);
  return v;
}

__device__ __forceinline__ float4 softmax4(float a, float b, float c, float d) {
  float mx = fmaxf(fmaxf(a, b), fmaxf(c, d));
  float e0 = expf(a - mx), e1 = expf(b - mx), e2 = expf(c - mx), e3 = expf(d - mx);
  float inv = 1.f / (e0 + e1 + e2 + e3);
  return make_float4(e0 * inv, e1 * inv, e2 * inv, e3 * inv);
}

// ---- CSR build ----------------------------------------------------------
__global__ void hist_rank(const int* __restrict__ ei, int* __restrict__ cnt,
                          int* __restrict__ rank, int E) {
  int e = blockIdx.x * blockDim.x + threadIdx.x;
  if (e >= E) return;
  int d = ei[E + e];
  rank[e] = atomicAdd(&cnt[d], 1);
}

__global__ void scanA(const int* __restrict__ cnt, int* __restrict__ out,
                      int* __restrict__ bsum, int N) {
  __shared__ int lds[256];
  int base = blockIdx.x * 1024 + threadIdx.x * 4;
  int v0 = (base + 0 < N) ? cnt[base + 0] : 0;
  int v1 = (base + 1 < N) ? cnt[base + 1] : 0;
  int v2 = (base + 2 < N) ? cnt[base + 2] : 0;
  int v3 = (base + 3 < N) ? cnt[base + 3] : 0;
  lds[threadIdx.x] = v0 + v1 + v2 + v3;
  __syncthreads();
  for (int off = 1; off < 256; off <<= 1) {
    int x = (threadIdx.x >= off) ? lds[threadIdx.x - off] : 0;
    __syncthreads();
    if (threadIdx.x >= off) lds[threadIdx.x] += x;
    __syncthreads();
  }
  int excl = (threadIdx.x == 0) ? 0 : lds[threadIdx.x - 1];
  if (threadIdx.x == 255) bsum[blockIdx.x] = lds[255];
  if (base + 0 < N) out[base + 0] = excl;
  if (base + 1 < N) out[base + 1] = excl + v0;
  if (base + 2 < N) out[base + 2] = excl + v0 + v1;
  if (base + 3 < N) out[base + 3] = excl + v0 + v1 + v2;
}

__global__ void scanB(int* __restrict__ bsum, int NB) {
  __shared__ int lds[256];
  int v = (threadIdx.x < NB) ? bsum[threadIdx.x] : 0;
  lds[threadIdx.x] = v;
  __syncthreads();
  for (int off = 1; off < 256; off <<= 1) {
    int x = (threadIdx.x >= off) ? lds[threadIdx.x - off] : 0;
    __syncthreads();
    if (threadIdx.x >= off) lds[threadIdx.x] += x;
    __syncthreads();
  }
  int excl = (threadIdx.x == 0) ? 0 : lds[threadIdx.x - 1];
  if (threadIdx.x < NB) bsum[threadIdx.x] = excl;
}

__global__ void scanC(int* __restrict__ rowStart, const int* __restrict__ bsum,
                      int N, int E) {
  int i = blockIdx.x * blockDim.x + threadIdx.x;
  if (i < N) rowStart[i] += bsum[i >> 10];
  if (i == 0) rowStart[N] = E;
}

__global__ void scatter_inc(const int* __restrict__ ei, const int* __restrict__ rowStart,
                            const int* __restrict__ rank, int* __restrict__ inc, int E) {
  int e = blockIdx.x * blockDim.x + threadIdx.x;
  if (e >= E) return;
  int d = ei[E + e];
  inc[rowStart[d] + rank[e]] = e;
}

__global__ void build_nodeOf(const int* __restrict__ rowStart, int* __restrict__ nodeOf,
                             int N) {
  int n = blockIdx.x * blockDim.x + threadIdx.x;
  if (n >= N) return;
  int s = rowStart[n], e = rowStart[n + 1];
  for (int k = s; k < e; ++k) nodeOf[k] = n;
}

// ---- per-pair setup: em, L0, two_m -------------------------------------
__global__ void setup_pairs(const float* __restrict__ w, const float* __restrict__ msg,
                            const float* __restrict__ beta_p, float* __restrict__ L,
                            float* __restrict__ em_buf, double* __restrict__ two_m,
                            int Eh) {
  int t = blockIdx.x * blockDim.x + threadIdx.x;
  float tw = 0.f;
  if (t < Eh) {
    float beta = beta_p[0];
    float wv = w[t];  // == w[t+Eh]
    tw = 2.f * wv;
    float em = expm1f(beta * wv);
    em_buf[t] = em;
    float4 m1 = *reinterpret_cast<const float4*>(&msg[(size_t)t * QD]);
    float4 m2 = *reinterpret_cast<const float4*>(&msg[((size_t)t + Eh) * QD]);
    float i1 = 1.f / (m1.x + m1.y + m1.z + m1.w);
    float i2 = 1.f / (m2.x + m2.y + m2.z + m2.w);
    float4 L1 = make_float4(log1pf(m1.x * i1 * em), log1pf(m1.y * i1 * em),
                            log1pf(m1.z * i1 * em), log1pf(m1.w * i1 * em));
    float4 L2 = make_float4(log1pf(m2.x * i2 * em), log1pf(m2.y * i2 * em),
                            log1pf(m2.z * i2 * em), log1pf(m2.w * i2 * em));
    *reinterpret_cast<float4*>(&L[(size_t)t * QD]) = L1;
    *reinterpret_cast<float4*>(&L[((size_t)t + Eh) * QD]) = L2;
  }
  tw = wave_red(tw);
  if ((threadIdx.x & 63) == 0 && tw != 0.f) atomicAdd(two_m, (double)tw);
}

// deg[n] = sum of w over incident edges (4 lanes per node) — one-time
__global__ void node_deg(const int* __restrict__ rowStart, const int* __restrict__ inc,
                         const float* __restrict__ w, float* __restrict__ deg, int N) {
  int gid = blockIdx.x * blockDim.x + threadIdx.x;
  int n = gid >> 2, sub = gid & 3;
  if (n >= N) return;
  int s = rowStart[n], e = rowStart[n + 1];
  float a = 0.f;
  for (int k = s + sub; k < e; k += 4) a += w[inc[k]];
  a += __shfl_xor(a, 1, 64);
  a += __shfl_xor(a, 2, 64);
  if (sub == 0) deg[n] = a;
}

// ---- v2 node phase ------------------------------------------------------
// One lane per CSR slot: single independent random L load, segmented
// shfl-scan by nodeOf, one float4 atomicAdd per segment end into S (zeroed).
__global__ void gatherL(const int* __restrict__ inc, const int* __restrict__ nodeOf,
                        const float* __restrict__ L, float* __restrict__ S, int E) {
  int k = blockIdx.x * blockDim.x + threadIdx.x;
  int lane = threadIdx.x & 63;
  bool valid = k < E;
  int n = valid ? nodeOf[k] : -1;
  int e = valid ? inc[k] : 0;
  float4 v = make_float4(0.f, 0.f, 0.f, 0.f);
  if (valid) v = *reinterpret_cast<const float4*>(&L[(size_t)e * QD]);
  // inclusive segmented scan over lanes with equal n
#pragma unroll
  for (int d = 1; d < 64; d <<= 1) {
    int nn = __shfl_up(n, d, 64);
    float vx = __shfl_up(v.x, d, 64);
    float vy = __shfl_up(v.y, d, 64);
    float vz = __shfl_up(v.z, d, 64);
    float vw = __shfl_up(v.w, d, 64);
    if (lane >= d && nn == n) { v.x += vx; v.y += vy; v.z += vz; v.w += vw; }
  }
  int ndown = __shfl_down(n, 1, 64);
  bool segend = (lane == 63) || (ndown != n);
  if (valid && segend) {
    atomicAdd(&S[(size_t)n * QD + 0], v.x);
    atomicAdd(&S[(size_t)n * QD + 1], v.y);
    atomicAdd(&S[(size_t)n * QD + 2], v.z);
    atomicAdd(&S[(size_t)n * QD + 3], v.w);
  }
}

// per-node: marg = softmax(h_prev + S); hsum_new += deg*marg
__global__ void node_post(const float* __restrict__ S, const float* __restrict__ deg,
                          const double* __restrict__ hsum_prev, double* __restrict__ hsum_new,
                          const float* __restrict__ beta_p, const double* __restrict__ two_m,
                          int N) {
  int n = blockIdx.x * blockDim.x + threadIdx.x;
  float scale = -beta_p[0] / (float)two_m[0];
  float h0 = scale * (float)hsum_prev[0];
  float h1 = scale * (float)hsum_prev[1];
  float h2 = scale * (float)hsum_prev[2];
  float h3 = scale * (float)hsum_prev[3];
  float a0 = 0.f, a1 = 0.f, a2 = 0.f, a3 = 0.f;
  if (n < N) {
    float4 Sv = *reinterpret_cast<const float4*>(&S[(size_t)n * QD]);
    float4 p = softmax4(h0 + Sv.x, h1 + Sv.y, h2 + Sv.z, h3 + Sv.w);
    float d = deg[n];
    a0 = d * p.x; a1 = d * p.y; a2 = d * p.z; a3 = d * p.w;
  }
  a0 = wave_red(a0); a1 = wave_red(a1); a2 = wave_red(a2); a3 = wave_red(a3);
  if ((threadIdx.x & 63) == 0) {
    atomicAdd(&hsum_new[0], (double)a0);
    atomicAdd(&hsum_new[1], (double)a1);
    atomicAdd(&hsum_new[2], (double)a2);
    atomicAdd(&hsum_new[3], (double)a3);
  }
}

// per-node final: s = softmax(h + S) -> out; comm_raw += deg*s
__global__ void node_post_final(const float* __restrict__ S, const float* __restrict__ deg,
                                const double* __restrict__ hsum, const float* __restrict__ beta_p,
                                const double* __restrict__ two_m, float* __restrict__ out_s,
                                double* __restrict__ comm_raw, int N) {
  int n = blockIdx.x * blockDim.x + threadIdx.x;
  float scale = -beta_p[0] / (float)two_m[0];
  float h0 = scale * (float)hsum[0];
  float h1 = scale * (float)hsum[1];
  float h2 = scale * (float)hsum[2];
  float h3 = scale * (float)hsum[3];
  float a0 = 0.f, a1 = 0.f, a2 = 0.f, a3 = 0.f;
  if (n < N) {
    float4 Sv = *reinterpret_cast<const float4*>(&S[(size_t)n * QD]);
    float4 p = softmax4(h0 + Sv.x, h1 + Sv.y, h2 + Sv.z, h3 + Sv.w);
    *reinterpret_cast<float4*>(&out_s[(size_t)n * QD]) = p;
    float d = deg[n];
    a0 = d * p.x; a1 = d * p.y; a2 = d * p.z; a3 = d * p.w;
  }
  a0 = wave_red(a0); a1 = wave_red(a1); a2 = wave_red(a2); a3 = wave_red(a3);
  if ((threadIdx.x & 63) == 0) {
    atomicAdd(&comm_raw[0], (double)a0);
    atomicAdd(&comm_raw[1], (double)a1);
    atomicAdd(&comm_raw[2], (double)a2);
    atomicAdd(&comm_raw[3], (double)a3);
  }
}

// ---- fallback (R3) node kernels ----------------------------------------
__global__ void node_step_old(const int* __restrict__ rowStart, const int* __restrict__ inc,
                              const float* __restrict__ L, const float* __restrict__ deg,
                              const double* __restrict__ hsum_prev, double* __restrict__ hsum_new,
                              const float* __restrict__ beta_p, const double* __restrict__ two_m,
                              float* __restrict__ S, int N) {
  int gid = blockIdx.x * blockDim.x + threadIdx.x;
  int n = gid >> 2, sub = gid & 3;
  float scale = -beta_p[0] / (float)two_m[0];
  float h0 = scale * (float)hsum_prev[0];
  float h1 = scale * (float)hsum_prev[1];
  float h2 = scale * (float)hsum_prev[2];
  float h3 = scale * (float)hsum_prev[3];
  float a0 = 0.f, a1 = 0.f, a2 = 0.f, a3 = 0.f;
  if (n < N) {
    int s = rowStart[n], e = rowStart[n + 1];
    float x0 = 0.f, x1 = 0.f, x2 = 0.f, x3 = 0.f;
    for (int k = s + sub; k < e; k += 4) {
      int eid = inc[k];
      float4 Lv = *reinterpret_cast<const float4*>(&L[(size_t)eid * QD]);
      x0 += Lv.x; x1 += Lv.y; x2 += Lv.z; x3 += Lv.w;
    }
#pragma unroll
    for (int m = 1; m <= 2; m <<= 1) {
      x0 += __shfl_xor(x0, m, 64);
      x1 += __shfl_xor(x1, m, 64);
      x2 += __shfl_xor(x2, m, 64);
      x3 += __shfl_xor(x3, m, 64);
    }
    if (sub == 0) {
      *reinterpret_cast<float4*>(&S[(size_t)n * QD]) = make_float4(x0, x1, x2, x3);
      float4 p = softmax4(h0 + x0, h1 + x1, h2 + x2, h3 + x3);
      float d = deg[n];
      a0 = d * p.x; a1 = d * p.y; a2 = d * p.z; a3 = d * p.w;
    }
  }
  a0 = wave_red(a0); a1 = wave_red(a1); a2 = wave_red(a2); a3 = wave_red(a3);
  if ((threadIdx.x & 63) == 0) {
    atomicAdd(&hsum_new[0], (double)a0);
    atomicAdd(&hsum_new[1], (double)a1);
    atomicAdd(&hsum_new[2], (double)a2);
    atomicAdd(&hsum_new[3], (double)a3);
  }
}

__global__ void node_final_old(const int* __restrict__ rowStart, const int* __restrict__ inc,
                               const float* __restrict__ L, const float* __restrict__ deg,
                               const double* __restrict__ hsum, const float* __restrict__ beta_p,
                               const double* __restrict__ two_m, float* __restrict__ out_s,
                               double* __restrict__ comm_raw, int N) {
  int gid = blockIdx.x * blockDim.x + threadIdx.x;
  int n = gid >> 2, sub = gid & 3;
  float scale = -beta_p[0] / (float)two_m[0];
  float h0 = scale * (float)hsum[0];
  float h1 = scale * (float)hsum[1];
  float h2 = scale * (float)hsum[2];
  float h3 = scale * (float)hsum[3];
  float a0 = 0.f, a1 = 0.f, a2 = 0.f, a3 = 0.f;
  if (n < N) {
    int s = rowStart[n], e = rowStart[n + 1];
    float x0 = 0.f, x1 = 0.f, x2 = 0.f, x3 = 0.f;
    for (int k = s + sub; k < e; k += 4) {
      int eid = inc[k];
      float4 Lv = *reinterpret_cast<const float4*>(&L[(size_t)eid * QD]);
      x0 += Lv.x; x1 += Lv.y; x2 += Lv.z; x3 += Lv.w;
    }
#pragma unroll
    for (int m = 1; m <= 2; m <<= 1) {
      x0 += __shfl_xor(x0, m, 64);
      x1 += __shfl_xor(x1, m, 64);
      x2 += __shfl_xor(x2, m, 64);
      x3 += __shfl_xor(x3, m, 64);
    }
    if (sub == 0) {
      float4 p = softmax4(h0 + x0, h1 + x1, h2 + x2, h3 + x3);
      *reinterpret_cast<float4*>(&out_s[(size_t)n * QD]) = p;
      float d = deg[n];
      a0 = d * p.x; a1 = d * p.y; a2 = d * p.z; a3 = d * p.w;
    }
  }
  a0 = wave_red(a0); a1 = wave_red(a1); a2 = wave_red(a2); a3 = wave_red(a3);
  if ((threadIdx.x & 63) == 0) {
    atomicAdd(&comm_raw[0], (double)a0);
    atomicAdd(&comm_raw[1], (double)a1);
    atomicAdd(&comm_raw[2], (double)a2);
    atomicAdd(&comm_raw[3], (double)a3);
  }
}

// cavity update, paired & in-place, zero atomics
__global__ void edge_step(const int* __restrict__ ei, const float* __restrict__ em_buf,
                          const float* __restrict__ S, float* __restrict__ L,
                          const double* __restrict__ hsum, const float* __restrict__ beta_p,
                          const double* __restrict__ two_m, int E, int Eh) {
  int t = blockIdx.x * blockDim.x + threadIdx.x;
  if (t >= Eh) return;
  float scale = -beta_p[0] / (float)two_m[0];
  float h0 = scale * (float)hsum[0];
  float h1 = scale * (float)hsum[1];
  float h2 = scale * (float)hsum[2];
  float h3 = scale * (float)hsum[3];
  int s1 = ei[t];
  int d1 = ei[E + t];
  float em = em_buf[t];
  float4 L1 = *reinterpret_cast<const float4*>(&L[(size_t)t * QD]);
  float4 L2 = *reinterpret_cast<const float4*>(&L[((size_t)t + Eh) * QD]);
  float4 Ss = *reinterpret_cast<const float4*>(&S[(size_t)s1 * QD]);
  float4 Sd = *reinterpret_cast<const float4*>(&S[(size_t)d1 * QD]);
  float4 p1 = softmax4(h0 + Ss.x - L2.x, h1 + Ss.y - L2.y,
                       h2 + Ss.z - L2.z, h3 + Ss.w - L2.w);
  float4 p2 = softmax4(h0 + Sd.x - L1.x, h1 + Sd.y - L1.y,
                       h2 + Sd.z - L1.z, h3 + Sd.w - L1.w);
  float4 n1 = make_float4(log1pf(p1.x * em), log1pf(p1.y * em),
                          log1pf(p1.z * em), log1pf(p1.w * em));
  float4 n2 = make_float4(log1pf(p2.x * em), log1pf(p2.y * em),
                          log1pf(p2.z * em), log1pf(p2.w * em));
  *reinterpret_cast<float4*>(&L[(size_t)t * QD]) = n1;
  *reinterpret_cast<float4*>(&L[((size_t)t + Eh) * QD]) = n2;
}

__global__ void edge_final(const int* __restrict__ ei, const float* __restrict__ w,
                           const float* __restrict__ out_s,
                           double* __restrict__ link_raw, int E, int Eh) {
  int t = blockIdx.x * blockDim.x + threadIdx.x;
  float c = 0.f;
  if (t < Eh) {
    int s1 = ei[t];
    int d1 = ei[E + t];
    float4 a = *reinterpret_cast<const float4*>(&out_s[(size_t)s1 * QD]);
    float4 b = *reinterpret_cast<const float4*>(&out_s[(size_t)d1 * QD]);
    float dot = a.x * b.x + a.y * b.y + a.z * b.z + a.w * b.w;
    c = 2.f * w[t] * dot;
  }
  c = wave_red(c);
  if ((threadIdx.x & 63) == 0 && c != 0.f) atomicAdd(link_raw, (double)c);
}

__global__ void finalize(const double* __restrict__ scal, float* __restrict__ out_q) {
  double tm = scal[0];
  double link = scal[1] / tm;
  double acc = 0.0;
#pragma unroll
  for (int k = 0; k < QD; ++k) {
    double c = scal[2 + k] / tm;
    acc += c * c;
  }
  out_q[0] = (float)(link - acc);
}

extern "C" void kernel_launch(void* const* d_in, const int* in_sizes, int n_in,
                              void* d_out, int out_size, void* d_ws, size_t ws_size,
                              hipStream_t stream) {
  const int* ei = (const int*)d_in[0];         // [2,E] int32
  const float* w = (const float*)d_in[1];      // [E]
  const float* msg = (const float*)d_in[2];    // [E,4]
  const float* beta_p = (const float*)d_in[3]; // scalar

  const int E = in_sizes[1];
  const int Eh = E / 2;
  const int N = (out_size - 1) / QD;

  // ws layout (R3-compatible prefix; nodeOf appended at the end)
  char* p = (char*)d_ws;
  double* scal = (double*)p;
  size_t off = 512;
  int* cnt = (int*)(p + off); off += (size_t)N * 4;
  int* rowStart = (int*)(p + off); off += (size_t)(N + 1) * 4;
  off = (off + 127) & ~(size_t)127;
  int* bsum = (int*)(p + off); off += 1024;
  int* inc = (int*)(p + off); off += (size_t)E * 4;
  float* deg = (float*)(p + off); off += (size_t)N * 4;
  off = (off + 15) & ~(size_t)15;
  float* S = (float*)(p + off); off += (size_t)N * QD * 4;
  float* em = (float*)(p + off); off += (size_t)Eh * 4;
  off = (off + 15) & ~(size_t)15;
  float* L = (float*)(p + off); off += (size_t)E * QD * 4;
  int* rank = (int*)L;  // alias: rank dead before L is first written
  int* nodeOf = (int*)(p + off); off += (size_t)E * 4;
  const bool v2 = ws_size >= off;  // host-side constant per process

  double* hs = scal + 6;  // hs + 4*i for iteration i's field accumulator
  const int gEdir = (E + NBLK - 1) / NBLK;
  const int gE = (Eh + NBLK - 1) / NBLK;
  const int gN = (N + NBLK - 1) / NBLK;
  const int gN4 = (4 * N + NBLK - 1) / NBLK;
  const int NBscan = (N + 1023) / 1024;

  hipMemsetAsync(scal, 0, 512, stream);
  hipMemsetAsync(cnt, 0, (size_t)N * 4, stream);

  hist_rank<<<gEdir, NBLK, 0, stream>>>(ei, cnt, rank, E);
  scanA<<<NBscan, 256, 0, stream>>>(cnt, rowStart, bsum, N);
  scanB<<<1, 256, 0, stream>>>(bsum, NBscan);
  scanC<<<(N + NBLK) / NBLK, NBLK, 0, stream>>>(rowStart, bsum, N, E);
  scatter_inc<<<gEdir, NBLK, 0, stream>>>(ei, rowStart, rank, inc, E);
  if (v2) build_nodeOf<<<gN, NBLK, 0, stream>>>(rowStart, nodeOf, N);

  setup_pairs<<<gE, NBLK, 0, stream>>>(w, msg, beta_p, L, em, scal, Eh);
  node_deg<<<gN4, NBLK, 0, stream>>>(rowStart, inc, w, deg, N);

  float* out_s = (float*)d_out;
  if (v2) {
    for (int i = 1; i <= 10; ++i) {
      hipMemsetAsync(S, 0, (size_t)N * QD * 4, stream);
      gatherL<<<gEdir, NBLK, 0, stream>>>(inc, nodeOf, L, S, E);
      node_post<<<gN, NBLK, 0, stream>>>(S, deg, hs + 4 * (i - 1), hs + 4 * i,
                                         beta_p, scal, N);
      edge_step<<<gE, NBLK, 0, stream>>>(ei, em, S, L, hs + 4 * i, beta_p, scal, E, Eh);
    }
    hipMemsetAsync(S, 0, (size_t)N * QD * 4, stream);
    gatherL<<<gEdir, NBLK, 0, stream>>>(inc, nodeOf, L, S, E);
    node_post_final<<<gN, NBLK, 0, stream>>>(S, deg, hs + 40, beta_p, scal,
                                             out_s, scal + 2, N);
  } else {
    for (int i = 1; i <= 10; ++i) {
      node_step_old<<<gN4, NBLK, 0, stream>>>(rowStart, inc, L, deg, hs + 4 * (i - 1),
                                              hs + 4 * i, beta_p, scal, S, N);
      edge_step<<<gE, NBLK, 0, stream>>>(ei, em, S, L, hs + 4 * i, beta_p, scal, E, Eh);
    }
    node_final_old<<<gN4, NBLK, 0, stream>>>(rowStart, inc, L, deg, hs + 40, beta_p,
                                             scal, out_s, scal + 2, N);
  }
  edge_final<<<gE, NBLK, 0, stream>>>(ei, w, out_s, scal + 1, E, Eh);
  finalize<<<1, 1, 0, stream>>>(scal, out_s + (size_t)N * QD);
}

// Round 7
// 1797.217 us; speedup vs baseline: 4.6983x; 1.5650x over previous
//
#include <hip/hip_runtime.h>

// CD_BP_Net: belief-propagation community detection on MI355X.
// R6 (resubmit; bench never ran):
//  - gather_seg: wave owns 256 CSR slots (4x64 windows), preloads 4 random
//    L loads upfront (4x MLP), segmented scan w/ inter-window carry; interior
//    segment sums are PLAIN STORES, only wave head/tail use atomics.
//  - same-address atomic storms removed: two_m via dedicated reduction;
//    node_post/edge_final use block-level LDS reduce (<=512 atomics/addr).
//  - deg via gather_seg<1> (replaces serialized node_deg loop).

#define NBLK 256
#define QD 4
#define SENT 0x7fffffff

__device__ __forceinline__ float wave_red(float v) {
#pragma unroll
  for (int o = 32; o > 0; o >>= 1) v += __shfl_down(v, o, 64);
  return v;
}

__device__ __forceinline__ float4 softmax4(float a, float b, float c, float d) {
  float mx = fmaxf(fmaxf(a, b), fmaxf(c, d));
  float e0 = expf(a - mx), e1 = expf(b - mx), e2 = expf(c - mx), e3 = expf(d - mx);
  float inv = 1.f / (e0 + e1 + e2 + e3);
  return make_float4(e0 * inv, e1 * inv, e2 * inv, e3 * inv);
}

// ---- CSR build ----------------------------------------------------------
// 4 edges per thread (strided) -> 4 independent atomics in flight.
__global__ void hist_rank(const int* __restrict__ ei, int* __restrict__ cnt,
                          int* __restrict__ rank, int E) {
  int G = gridDim.x * blockDim.x;
  int e0 = blockIdx.x * blockDim.x + threadIdx.x;
  int e1 = e0 + G, e2 = e0 + 2 * G, e3 = e0 + 3 * G;
  int d0 = (e0 < E) ? ei[E + e0] : 0;
  int d1 = (e1 < E) ? ei[E + e1] : 0;
  int d2 = (e2 < E) ? ei[E + e2] : 0;
  int d3 = (e3 < E) ? ei[E + e3] : 0;
  if (e0 < E) rank[e0] = atomicAdd(&cnt[d0], 1);
  if (e1 < E) rank[e1] = atomicAdd(&cnt[d1], 1);
  if (e2 < E) rank[e2] = atomicAdd(&cnt[d2], 1);
  if (e3 < E) rank[e3] = atomicAdd(&cnt[d3], 1);
}

__global__ void scanA(const int* __restrict__ cnt, int* __restrict__ out,
                      int* __restrict__ bsum, int N) {
  __shared__ int lds[256];
  int base = blockIdx.x * 1024 + threadIdx.x * 4;
  int v0 = (base + 0 < N) ? cnt[base + 0] : 0;
  int v1 = (base + 1 < N) ? cnt[base + 1] : 0;
  int v2 = (base + 2 < N) ? cnt[base + 2] : 0;
  int v3 = (base + 3 < N) ? cnt[base + 3] : 0;
  lds[threadIdx.x] = v0 + v1 + v2 + v3;
  __syncthreads();
  for (int off = 1; off < 256; off <<= 1) {
    int x = (threadIdx.x >= off) ? lds[threadIdx.x - off] : 0;
    __syncthreads();
    if (threadIdx.x >= off) lds[threadIdx.x] += x;
    __syncthreads();
  }
  int excl = (threadIdx.x == 0) ? 0 : lds[threadIdx.x - 1];
  if (threadIdx.x == 255) bsum[blockIdx.x] = lds[255];
  if (base + 0 < N) out[base + 0] = excl;
  if (base + 1 < N) out[base + 1] = excl + v0;
  if (base + 2 < N) out[base + 2] = excl + v0 + v1;
  if (base + 3 < N) out[base + 3] = excl + v0 + v1 + v2;
}

__global__ void scanB(int* __restrict__ bsum, int NB) {
  __shared__ int lds[256];
  int v = (threadIdx.x < NB) ? bsum[threadIdx.x] : 0;
  lds[threadIdx.x] = v;
  __syncthreads();
  for (int off = 1; off < 256; off <<= 1) {
    int x = (threadIdx.x >= off) ? lds[threadIdx.x - off] : 0;
    __syncthreads();
    if (threadIdx.x >= off) lds[threadIdx.x] += x;
    __syncthreads();
  }
  int excl = (threadIdx.x == 0) ? 0 : lds[threadIdx.x - 1];
  if (threadIdx.x < NB) bsum[threadIdx.x] = excl;
}

__global__ void scanC(int* __restrict__ rowStart, const int* __restrict__ bsum,
                      int N, int E) {
  int i = blockIdx.x * blockDim.x + threadIdx.x;
  if (i < N) rowStart[i] += bsum[i >> 10];
  if (i == 0) rowStart[N] = E;
}

__global__ void scatter_inc(const int* __restrict__ ei, const int* __restrict__ rowStart,
                            const int* __restrict__ rank, int* __restrict__ inc, int E) {
  int e = blockIdx.x * blockDim.x + threadIdx.x;
  if (e >= E) return;
  int d = ei[E + e];
  inc[rowStart[d] + rank[e]] = e;
}

__global__ void build_nodeOf(const int* __restrict__ rowStart, int* __restrict__ nodeOf,
                             int N) {
  int n = blockIdx.x * blockDim.x + threadIdx.x;
  if (n >= N) return;
  int s = rowStart[n], e = rowStart[n + 1];
  for (int k = s; k < e; ++k) nodeOf[k] = n;
}

// ---- two_m = sum(edge_attr) over all E, no same-address storm ----------
__global__ void reduce_w(const float* __restrict__ w, double* __restrict__ two_m, int E) {
  __shared__ float blk[4];
  int G = gridDim.x * blockDim.x;
  float acc = 0.f;
  for (int i = blockIdx.x * blockDim.x + threadIdx.x; i < E; i += G) acc += w[i];
  acc = wave_red(acc);
  int wid = threadIdx.x >> 6;
  if ((threadIdx.x & 63) == 0) blk[wid] = acc;
  __syncthreads();
  if (threadIdx.x == 0)
    atomicAdd(two_m, (double)(blk[0] + blk[1] + blk[2] + blk[3]));
}

// ---- per-pair setup: em, L0 (no atomics) -------------------------------
__global__ void setup_pairs(const float* __restrict__ w, const float* __restrict__ msg,
                            const float* __restrict__ beta_p, float* __restrict__ L,
                            float* __restrict__ em_buf, int Eh) {
  int t = blockIdx.x * blockDim.x + threadIdx.x;
  if (t >= Eh) return;
  float beta = beta_p[0];
  float wv = w[t];  // == w[t+Eh]
  float em = expm1f(beta * wv);
  em_buf[t] = em;
  float4 m1 = *reinterpret_cast<const float4*>(&msg[(size_t)t * QD]);
  float4 m2 = *reinterpret_cast<const float4*>(&msg[((size_t)t + Eh) * QD]);
  float i1 = 1.f / (m1.x + m1.y + m1.z + m1.w);
  float i2 = 1.f / (m2.x + m2.y + m2.z + m2.w);
  float4 L1 = make_float4(log1pf(m1.x * i1 * em), log1pf(m1.y * i1 * em),
                          log1pf(m1.z * i1 * em), log1pf(m1.w * i1 * em));
  float4 L2 = make_float4(log1pf(m2.x * i2 * em), log1pf(m2.y * i2 * em),
                          log1pf(m2.z * i2 * em), log1pf(m2.w * i2 * em));
  *reinterpret_cast<float4*>(&L[(size_t)t * QD]) = L1;
  *reinterpret_cast<float4*>(&L[((size_t)t + Eh) * QD]) = L2;
}

// ---- gather with segmented scan, 4x MLP --------------------------------
// Wave owns 256 consecutive CSR slots (4 windows of 64). Preloads all 4
// random src loads upfront. Interior segment sums: plain stores. Only the
// wave's head-spanning node and trailing partial use atomicAdd.
// out must be zeroed (atomic targets accumulate).
template <int NC>
__global__ void gather_seg(const int* __restrict__ inc, const int* __restrict__ nodeOf,
                           const float* __restrict__ src, float* __restrict__ out,
                           int E) {
  const int lane = threadIdx.x & 63;
  const int wid = threadIdx.x >> 6;
  const long long base = ((long long)blockIdx.x * (blockDim.x >> 6) + wid) * 256;
  if (base >= E) return;
  int n[4], idx[4];
  float v[4][NC];
#pragma unroll
  for (int w = 0; w < 4; ++w) {
    long long k = base + w * 64 + lane;
    n[w] = (k < E) ? nodeOf[k] : SENT;
    idx[w] = (k < E) ? inc[k] : 0;
  }
#pragma unroll
  for (int w = 0; w < 4; ++w) {
    long long k = base + w * 64 + lane;
    if (k < E) {
      if constexpr (NC == 4) {
        float4 t = *reinterpret_cast<const float4*>(&src[(size_t)idx[w] * 4]);
        v[w][0] = t.x; v[w][1] = t.y; v[w][2] = t.z; v[w][3] = t.w;
      } else {
        v[w][0] = src[idx[w]];
      }
    } else {
#pragma unroll
      for (int c = 0; c < NC; ++c) v[w][c] = 0.f;
    }
  }
  int n00 = __shfl(n[0], 0, 64);
  int prevn = (base > 0) ? nodeOf[base - 1] : -1;
  const int incomplete = (prevn == n00) ? n00 : -1;
  int nwf[4];
#pragma unroll
  for (int w = 0; w < 3; ++w) nwf[w] = __shfl(n[w + 1], 0, 64);
  nwf[3] = (base + 256 < E) ? nodeOf[base + 256] : -1;

  float cv[NC];
#pragma unroll
  for (int c = 0; c < NC; ++c) cv[c] = 0.f;
  int cn = -1;
#pragma unroll
  for (int w = 0; w < 4; ++w) {
    int nn = n[w];
    // segmented inclusive scan keyed by nn (nodeOf is non-decreasing)
#pragma unroll
    for (int d = 1; d < 64; d <<= 1) {
      int pn = __shfl_up(nn, d, 64);
      float pv[NC];
#pragma unroll
      for (int c = 0; c < NC; ++c) pv[c] = __shfl_up(v[w][c], d, 64);
      if (lane >= d && pn == nn) {
#pragma unroll
        for (int c = 0; c < NC; ++c) v[w][c] += pv[c];
      }
    }
    // carry from previous window (head run only; nodeOf sorted)
    if (nn == cn) {
#pragma unroll
      for (int c = 0; c < NC; ++c) v[w][c] += cv[c];
    }
    int nnext = __shfl_down(nn, 1, 64);
    if (lane == 63) nnext = nwf[w];
    bool segend = (nn != SENT) && (nnext != nn);
    if (segend) {
      if (nn == incomplete) {
#pragma unroll
        for (int c = 0; c < NC; ++c) atomicAdd(&out[(size_t)nn * NC + c], v[w][c]);
      } else {
        if constexpr (NC == 4) {
          *reinterpret_cast<float4*>(&out[(size_t)nn * 4]) =
              make_float4(v[w][0], v[w][1], v[w][2], v[w][3]);
        } else {
          out[nn] = v[w][0];
        }
      }
    }
    // carry out from lane 63
    int last_n = __shfl(nn, 63, 64);
    float lv[NC];
#pragma unroll
    for (int c = 0; c < NC; ++c) lv[c] = __shfl(v[w][c], 63, 64);
    bool last_end = (nwf[w] != last_n) || (last_n == SENT);
    if (last_end) {
      cn = -1;
#pragma unroll
      for (int c = 0; c < NC; ++c) cv[c] = 0.f;
    } else {
      cn = last_n;
#pragma unroll
      for (int c = 0; c < NC; ++c) cv[c] = lv[c];
    }
  }
  if (cn != -1 && lane == 0) {
#pragma unroll
    for (int c = 0; c < NC; ++c) atomicAdd(&out[(size_t)cn * NC + c], cv[c]);
  }
}

// ---- per-node: marg = softmax(h_prev + S); hsum_new += deg*marg --------
__global__ void node_post(const float* __restrict__ S, const float* __restrict__ deg,
                          const double* __restrict__ hsum_prev, double* __restrict__ hsum_new,
                          const float* __restrict__ beta_p, const double* __restrict__ two_m,
                          int N) {
  __shared__ float blk[4][4];
  int n = blockIdx.x * blockDim.x + threadIdx.x;
  float scale = -beta_p[0] / (float)two_m[0];
  float h0 = scale * (float)hsum_prev[0];
  float h1 = scale * (float)hsum_prev[1];
  float h2 = scale * (float)hsum_prev[2];
  float h3 = scale * (float)hsum_prev[3];
  float a0 = 0.f, a1 = 0.f, a2 = 0.f, a3 = 0.f;
  if (n < N) {
    float4 Sv = *reinterpret_cast<const float4*>(&S[(size_t)n * QD]);
    float4 p = softmax4(h0 + Sv.x, h1 + Sv.y, h2 + Sv.z, h3 + Sv.w);
    float d = deg[n];
    a0 = d * p.x; a1 = d * p.y; a2 = d * p.z; a3 = d * p.w;
  }
  a0 = wave_red(a0); a1 = wave_red(a1); a2 = wave_red(a2); a3 = wave_red(a3);
  int wid = threadIdx.x >> 6;
  if ((threadIdx.x & 63) == 0) {
    blk[wid][0] = a0; blk[wid][1] = a1; blk[wid][2] = a2; blk[wid][3] = a3;
  }
  __syncthreads();
  if (threadIdx.x < 4) {
    float s = blk[0][threadIdx.x] + blk[1][threadIdx.x] + blk[2][threadIdx.x] +
              blk[3][threadIdx.x];
    atomicAdd(&hsum_new[threadIdx.x], (double)s);
  }
}

__global__ void node_post_final(const float* __restrict__ S, const float* __restrict__ deg,
                                const double* __restrict__ hsum, const float* __restrict__ beta_p,
                                const double* __restrict__ two_m, float* __restrict__ out_s,
                                double* __restrict__ comm_raw, int N) {
  __shared__ float blk[4][4];
  int n = blockIdx.x * blockDim.x + threadIdx.x;
  float scale = -beta_p[0] / (float)two_m[0];
  float h0 = scale * (float)hsum[0];
  float h1 = scale * (float)hsum[1];
  float h2 = scale * (float)hsum[2];
  float h3 = scale * (float)hsum[3];
  float a0 = 0.f, a1 = 0.f, a2 = 0.f, a3 = 0.f;
  if (n < N) {
    float4 Sv = *reinterpret_cast<const float4*>(&S[(size_t)n * QD]);
    float4 p = softmax4(h0 + Sv.x, h1 + Sv.y, h2 + Sv.z, h3 + Sv.w);
    *reinterpret_cast<float4*>(&out_s[(size_t)n * QD]) = p;
    float d = deg[n];
    a0 = d * p.x; a1 = d * p.y; a2 = d * p.z; a3 = d * p.w;
  }
  a0 = wave_red(a0); a1 = wave_red(a1); a2 = wave_red(a2); a3 = wave_red(a3);
  int wid = threadIdx.x >> 6;
  if ((threadIdx.x & 63) == 0) {
    blk[wid][0] = a0; blk[wid][1] = a1; blk[wid][2] = a2; blk[wid][3] = a3;
  }
  __syncthreads();
  if (threadIdx.x < 4) {
    float s = blk[0][threadIdx.x] + blk[1][threadIdx.x] + blk[2][threadIdx.x] +
              blk[3][threadIdx.x];
    atomicAdd(&comm_raw[threadIdx.x], (double)s);
  }
}

// cavity update, paired & in-place, zero atomics
__global__ void edge_step(const int* __restrict__ ei, const float* __restrict__ em_buf,
                          const float* __restrict__ S, float* __restrict__ L,
                          const double* __restrict__ hsum, const float* __restrict__ beta_p,
                          const double* __restrict__ two_m, int E, int Eh) {
  int t = blockIdx.x * blockDim.x + threadIdx.x;
  if (t >= Eh) return;
  float scale = -beta_p[0] / (float)two_m[0];
  float h0 = scale * (float)hsum[0];
  float h1 = scale * (float)hsum[1];
  float h2 = scale * (float)hsum[2];
  float h3 = scale * (float)hsum[3];
  int s1 = ei[t];
  int d1 = ei[E + t];
  float em = em_buf[t];
  float4 L1 = *reinterpret_cast<const float4*>(&L[(size_t)t * QD]);
  float4 L2 = *reinterpret_cast<const float4*>(&L[((size_t)t + Eh) * QD]);
  float4 Ss = *reinterpret_cast<const float4*>(&S[(size_t)s1 * QD]);
  float4 Sd = *reinterpret_cast<const float4*>(&S[(size_t)d1 * QD]);
  float4 p1 = softmax4(h0 + Ss.x - L2.x, h1 + Ss.y - L2.y,
                       h2 + Ss.z - L2.z, h3 + Ss.w - L2.w);
  float4 p2 = softmax4(h0 + Sd.x - L1.x, h1 + Sd.y - L1.y,
                       h2 + Sd.z - L1.z, h3 + Sd.w - L1.w);
  float4 n1 = make_float4(log1pf(p1.x * em), log1pf(p1.y * em),
                          log1pf(p1.z * em), log1pf(p1.w * em));
  float4 n2 = make_float4(log1pf(p2.x * em), log1pf(p2.y * em),
                          log1pf(p2.z * em), log1pf(p2.w * em));
  *reinterpret_cast<float4*>(&L[(size_t)t * QD]) = n1;
  *reinterpret_cast<float4*>(&L[((size_t)t + Eh) * QD]) = n2;
}

// link: grid-stride + block reduce -> <=512 same-address atomics
__global__ void edge_final(const int* __restrict__ ei, const float* __restrict__ w,
                           const float* __restrict__ out_s,
                           double* __restrict__ link_raw, int E, int Eh) {
  __shared__ float blk[4];
  int G = gridDim.x * blockDim.x;
  float c = 0.f;
  for (int t = blockIdx.x * blockDim.x + threadIdx.x; t < Eh; t += G) {
    int s1 = ei[t];
    int d1 = ei[E + t];
    float4 a = *reinterpret_cast<const float4*>(&out_s[(size_t)s1 * QD]);
    float4 b = *reinterpret_cast<const float4*>(&out_s[(size_t)d1 * QD]);
    float dot = a.x * b.x + a.y * b.y + a.z * b.z + a.w * b.w;
    c += 2.f * w[t] * dot;
  }
  c = wave_red(c);
  int wid = threadIdx.x >> 6;
  if ((threadIdx.x & 63) == 0) blk[wid] = c;
  __syncthreads();
  if (threadIdx.x == 0)
    atomicAdd(link_raw, (double)(blk[0] + blk[1] + blk[2] + blk[3]));
}

__global__ void finalize(const double* __restrict__ scal, float* __restrict__ out_q) {
  double tm = scal[0];
  double link = scal[1] / tm;
  double acc = 0.0;
#pragma unroll
  for (int k = 0; k < QD; ++k) {
    double c = scal[2 + k] / tm;
    acc += c * c;
  }
  out_q[0] = (float)(link - acc);
}

extern "C" void kernel_launch(void* const* d_in, const int* in_sizes, int n_in,
                              void* d_out, int out_size, void* d_ws, size_t ws_size,
                              hipStream_t stream) {
  const int* ei = (const int*)d_in[0];         // [2,E] int32
  const float* w = (const float*)d_in[1];      // [E]
  const float* msg = (const float*)d_in[2];    // [E,4]
  const float* beta_p = (const float*)d_in[3]; // scalar

  const int E = in_sizes[1];
  const int Eh = E / 2;
  const int N = (out_size - 1) / QD;

  // ws layout: scal [0]=two_m [1]=link [2..5]=comm [6+4i..]=hsum (i=0..10)
  char* p = (char*)d_ws;
  double* scal = (double*)p;
  size_t off = 512;
  int* cnt = (int*)(p + off); off += (size_t)N * 4;
  int* rowStart = (int*)(p + off); off += (size_t)(N + 1) * 4;
  off = (off + 127) & ~(size_t)127;
  int* bsum = (int*)(p + off); off += 1024;
  int* inc = (int*)(p + off); off += (size_t)E * 4;
  float* deg = (float*)(p + off); off += (size_t)N * 4;
  off = (off + 15) & ~(size_t)15;
  float* S = (float*)(p + off); off += (size_t)N * QD * 4;
  float* em = (float*)(p + off); off += (size_t)Eh * 4;
  off = (off + 15) & ~(size_t)15;
  float* L = (float*)(p + off); off += (size_t)E * QD * 4;
  int* rank = (int*)L;  // alias: rank dead before L is first written
  int* nodeOf = (int*)(p + off); off += (size_t)E * 4;
  (void)ws_size;

  double* hs = scal + 6;
  const int gEdir = (E + NBLK - 1) / NBLK;
  const int gE = (Eh + NBLK - 1) / NBLK;
  const int gN = (N + NBLK - 1) / NBLK;
  const int gH = (E + NBLK * 4 - 1) / (NBLK * 4);
  const int gW = (E + 1023) / 1024;  // gather_seg: 1024 slots/block
  const int NBscan = (N + 1023) / 1024;

  hipMemsetAsync(scal, 0, 512, stream);
  hipMemsetAsync(cnt, 0, (size_t)N * 4, stream);
  hipMemsetAsync(deg, 0, (size_t)N * 4, stream);

  hist_rank<<<gH, NBLK, 0, stream>>>(ei, cnt, rank, E);
  scanA<<<NBscan, 256, 0, stream>>>(cnt, rowStart, bsum, N);
  scanB<<<1, 256, 0, stream>>>(bsum, NBscan);
  scanC<<<(N + NBLK) / NBLK, NBLK, 0, stream>>>(rowStart, bsum, N, E);
  scatter_inc<<<gEdir, NBLK, 0, stream>>>(ei, rowStart, rank, inc, E);
  build_nodeOf<<<gN, NBLK, 0, stream>>>(rowStart, nodeOf, N);

  reduce_w<<<256, NBLK, 0, stream>>>(w, scal, E);
  setup_pairs<<<gE, NBLK, 0, stream>>>(w, msg, beta_p, L, em, Eh);
  gather_seg<1><<<gW, NBLK, 0, stream>>>(inc, nodeOf, w, deg, E);

  float* out_s = (float*)d_out;
  for (int i = 1; i <= 10; ++i) {
    hipMemsetAsync(S, 0, (size_t)N * QD * 4, stream);
    gather_seg<4><<<gW, NBLK, 0, stream>>>(inc, nodeOf, L, S, E);
    node_post<<<gN, NBLK, 0, stream>>>(S, deg, hs + 4 * (i - 1), hs + 4 * i,
                                       beta_p, scal, N);
    edge_step<<<gE, NBLK, 0, stream>>>(ei, em, S, L, hs + 4 * i, beta_p, scal, E, Eh);
  }
  hipMemsetAsync(S, 0, (size_t)N * QD * 4, stream);
  gather_seg<4><<<gW, NBLK, 0, stream>>>(inc, nodeOf, L, S, E);
  node_post_final<<<gN, NBLK, 0, stream>>>(S, deg, hs + 40, beta_p, scal,
                                           out_s, scal + 2, N);
  edge_final<<<512, NBLK, 0, stream>>>(ei, w, out_s, scal + 1, E, Eh);
  finalize<<<1, 1, 0, stream>>>(scal, out_s + (size_t)N * QD);
}

// Round 8
// 1719.139 us; speedup vs baseline: 4.9117x; 1.0454x over previous
//
#include <hip/hip_runtime.h>

// CD_BP_Net R8: log-free product-form BP.
//  Edge state F = 1 + psi*em  (so L = ln F, exp(S) = prod F).
//  - gather_prod: segmented PRODUCT of F[inc[k]] by dst -> P[n] (= e^S).
//    8 windows/wave (8 random loads in flight); interior stores; CAS-mult
//    boundaries; P pre-filled with 1.0.
//  - node_post: marg = eh*P / sum (no softmax/exp besides 4 scalar exps).
//  - edge_fuse: psi1_k ∝ eh_k*P[src]_k/F2_k via exclusive products; 1 div
//    per direction; F updated in place. ZERO per-edge transcendentals.
//  - setup folds two_m reduction into setup_pairs; hist 8-way MLP.

#define NBLK 256
#define QD 4
#define SENT 0x7fffffff

__device__ __forceinline__ float wave_red(float v) {
#pragma unroll
  for (int o = 32; o > 0; o >>= 1) v += __shfl_down(v, o, 64);
  return v;
}

__device__ __forceinline__ void atomicMulF(float* addr, float val) {
  unsigned int old = __float_as_uint(*addr), assumed;
  do {
    assumed = old;
    float nv = __uint_as_float(assumed) * val;
    old = atomicCAS((unsigned int*)addr, assumed, __float_as_uint(nv));
  } while (old != assumed);
}

// ---- CSR build ----------------------------------------------------------
__global__ void hist_rank(const int* __restrict__ ei, int* __restrict__ cnt,
                          int* __restrict__ rank, int E) {
  int G = gridDim.x * blockDim.x;
  int e[8], d[8];
#pragma unroll
  for (int j = 0; j < 8; ++j) {
    e[j] = blockIdx.x * blockDim.x + threadIdx.x + j * G;
    d[j] = (e[j] < E) ? ei[E + e[j]] : 0;
  }
#pragma unroll
  for (int j = 0; j < 8; ++j)
    if (e[j] < E) rank[e[j]] = atomicAdd(&cnt[d[j]], 1);
}

__global__ void scanA(const int* __restrict__ cnt, int* __restrict__ out,
                      int* __restrict__ bsum, int N) {
  __shared__ int lds[256];
  int base = blockIdx.x * 1024 + threadIdx.x * 4;
  int v0 = (base + 0 < N) ? cnt[base + 0] : 0;
  int v1 = (base + 1 < N) ? cnt[base + 1] : 0;
  int v2 = (base + 2 < N) ? cnt[base + 2] : 0;
  int v3 = (base + 3 < N) ? cnt[base + 3] : 0;
  lds[threadIdx.x] = v0 + v1 + v2 + v3;
  __syncthreads();
  for (int off = 1; off < 256; off <<= 1) {
    int x = (threadIdx.x >= off) ? lds[threadIdx.x - off] : 0;
    __syncthreads();
    if (threadIdx.x >= off) lds[threadIdx.x] += x;
    __syncthreads();
  }
  int excl = (threadIdx.x == 0) ? 0 : lds[threadIdx.x - 1];
  if (threadIdx.x == 255) bsum[blockIdx.x] = lds[255];
  if (base + 0 < N) out[base + 0] = excl;
  if (base + 1 < N) out[base + 1] = excl + v0;
  if (base + 2 < N) out[base + 2] = excl + v0 + v1;
  if (base + 3 < N) out[base + 3] = excl + v0 + v1 + v2;
}

__global__ void scanB(int* __restrict__ bsum, int NB) {
  __shared__ int lds[256];
  int v = (threadIdx.x < NB) ? bsum[threadIdx.x] : 0;
  lds[threadIdx.x] = v;
  __syncthreads();
  for (int off = 1; off < 256; off <<= 1) {
    int x = (threadIdx.x >= off) ? lds[threadIdx.x - off] : 0;
    __syncthreads();
    if (threadIdx.x >= off) lds[threadIdx.x] += x;
    __syncthreads();
  }
  int excl = (threadIdx.x == 0) ? 0 : lds[threadIdx.x - 1];
  if (threadIdx.x < NB) bsum[threadIdx.x] = excl;
}

__global__ void scanC(int* __restrict__ rowStart, const int* __restrict__ bsum,
                      int N, int E) {
  int i = blockIdx.x * blockDim.x + threadIdx.x;
  if (i < N) rowStart[i] += bsum[i >> 10];
  if (i == 0) rowStart[N] = E;
}

__global__ void scatter_inc(const int* __restrict__ ei, const int* __restrict__ rowStart,
                            const int* __restrict__ rank, int* __restrict__ inc, int E) {
  int G = gridDim.x * blockDim.x;
#pragma unroll
  for (int j = 0; j < 4; ++j) {
    int e = blockIdx.x * blockDim.x + threadIdx.x + j * G;
    if (e < E) {
      int d = ei[E + e];
      inc[rowStart[d] + rank[e]] = e;
    }
  }
}

__global__ void build_nodeOf(const int* __restrict__ rowStart, int* __restrict__ nodeOf,
                             int N) {
  int n = blockIdx.x * blockDim.x + threadIdx.x;
  if (n >= N) return;
  int s = rowStart[n], e = rowStart[n + 1];
  for (int k = s; k < e; ++k) nodeOf[k] = n;
}

// ---- setup: em, F0 = 1 + psi0*em, two_m (block-reduced) ----------------
__global__ void setup_pairs(const float* __restrict__ w, const float* __restrict__ msg,
                            const float* __restrict__ beta_p, float* __restrict__ F,
                            float* __restrict__ em_buf, double* __restrict__ two_m,
                            int Eh) {
  __shared__ float blk[4];
  int t = blockIdx.x * blockDim.x + threadIdx.x;
  float tw = 0.f;
  if (t < Eh) {
    float beta = beta_p[0];
    float wv = w[t];  // == w[t+Eh]
    tw = 2.f * wv;
    float em = expm1f(beta * wv);
    em_buf[t] = em;
    float4 m1 = *reinterpret_cast<const float4*>(&msg[(size_t)t * QD]);
    float4 m2 = *reinterpret_cast<const float4*>(&msg[((size_t)t + Eh) * QD]);
    float i1 = em / (m1.x + m1.y + m1.z + m1.w);
    float i2 = em / (m2.x + m2.y + m2.z + m2.w);
    float4 F1 = make_float4(fmaf(m1.x, i1, 1.f), fmaf(m1.y, i1, 1.f),
                            fmaf(m1.z, i1, 1.f), fmaf(m1.w, i1, 1.f));
    float4 F2 = make_float4(fmaf(m2.x, i2, 1.f), fmaf(m2.y, i2, 1.f),
                            fmaf(m2.z, i2, 1.f), fmaf(m2.w, i2, 1.f));
    *reinterpret_cast<float4*>(&F[(size_t)t * QD]) = F1;
    *reinterpret_cast<float4*>(&F[((size_t)t + Eh) * QD]) = F2;
  }
  tw = wave_red(tw);
  int wid = threadIdx.x >> 6;
  if ((threadIdx.x & 63) == 0) blk[wid] = tw;
  __syncthreads();
  if (threadIdx.x == 0)
    atomicAdd(two_m, (double)(blk[0] + blk[1] + blk[2] + blk[3]));
}

__global__ void fillP(float* __restrict__ P, int n4) {
  int i = blockIdx.x * blockDim.x + threadIdx.x;
  if (i < n4) P[i] = 1.0f;
}

// ---- segmented gather: NW windows of 64 slots per wave ------------------
// PROD: combine by multiply, identity 1, CAS-mult boundaries (P pre-filled 1).
// !PROD: combine by add, identity 0, atomicAdd boundaries (out pre-zeroed).
template <int NC, bool PROD, int NW>
__global__ void gather_seg(const int* __restrict__ inc, const int* __restrict__ nodeOf,
                           const float* __restrict__ src, float* __restrict__ out,
                           int E) {
  const int lane = threadIdx.x & 63;
  const int wid = threadIdx.x >> 6;
  const long long base = ((long long)blockIdx.x * (blockDim.x >> 6) + wid) * (NW * 64);
  if (base >= E) return;
  const float IDENT = PROD ? 1.f : 0.f;
  int n[NW], idx[NW];
  float v[NW][NC];
#pragma unroll
  for (int w = 0; w < NW; ++w) {
    long long k = base + w * 64 + lane;
    n[w] = (k < E) ? nodeOf[k] : SENT;
    idx[w] = (k < E) ? inc[k] : 0;
  }
#pragma unroll
  for (int w = 0; w < NW; ++w) {
    long long k = base + w * 64 + lane;
    if (k < E) {
      if constexpr (NC == 4) {
        float4 t = *reinterpret_cast<const float4*>(&src[(size_t)idx[w] * 4]);
        v[w][0] = t.x; v[w][1] = t.y; v[w][2] = t.z; v[w][3] = t.w;
      } else {
        v[w][0] = src[idx[w]];
      }
    } else {
#pragma unroll
      for (int c = 0; c < NC; ++c) v[w][c] = IDENT;
    }
  }
  int n00 = __shfl(n[0], 0, 64);
  int prevn = (base > 0) ? nodeOf[base - 1] : -1;
  const int incomplete = (prevn == n00) ? n00 : -1;
  int nwf[NW];
#pragma unroll
  for (int w = 0; w < NW - 1; ++w) nwf[w] = __shfl(n[w + 1], 0, 64);
  nwf[NW - 1] = (base + NW * 64 < E) ? nodeOf[base + NW * 64] : -1;

  float cv[NC];
#pragma unroll
  for (int c = 0; c < NC; ++c) cv[c] = IDENT;
  int cn = -1;
#pragma unroll
  for (int w = 0; w < NW; ++w) {
    int nn = n[w];
#pragma unroll
    for (int d = 1; d < 64; d <<= 1) {
      int pn = __shfl_up(nn, d, 64);
      float pv[NC];
#pragma unroll
      for (int c = 0; c < NC; ++c) pv[c] = __shfl_up(v[w][c], d, 64);
      if (lane >= d && pn == nn) {
#pragma unroll
        for (int c = 0; c < NC; ++c) {
          if constexpr (PROD) v[w][c] *= pv[c]; else v[w][c] += pv[c];
        }
      }
    }
    if (nn == cn) {
#pragma unroll
      for (int c = 0; c < NC; ++c) {
        if constexpr (PROD) v[w][c] *= cv[c]; else v[w][c] += cv[c];
      }
    }
    int nnext = __shfl_down(nn, 1, 64);
    if (lane == 63) nnext = nwf[w];
    bool segend = (nn != SENT) && (nnext != nn);
    if (segend) {
      if (nn == incomplete) {
#pragma unroll
        for (int c = 0; c < NC; ++c) {
          if constexpr (PROD) atomicMulF(&out[(size_t)nn * NC + c], v[w][c]);
          else atomicAdd(&out[(size_t)nn * NC + c], v[w][c]);
        }
      } else {
        if constexpr (NC == 4) {
          *reinterpret_cast<float4*>(&out[(size_t)nn * 4]) =
              make_float4(v[w][0], v[w][1], v[w][2], v[w][3]);
        } else {
          out[nn] = v[w][0];
        }
      }
    }
    int last_n = __shfl(nn, 63, 64);
    float lv[NC];
#pragma unroll
    for (int c = 0; c < NC; ++c) lv[c] = __shfl(v[w][c], 63, 64);
    bool last_end = (nwf[w] != last_n) || (last_n == SENT);
    if (last_end) {
      cn = -1;
#pragma unroll
      for (int c = 0; c < NC; ++c) cv[c] = IDENT;
    } else {
      cn = last_n;
#pragma unroll
      for (int c = 0; c < NC; ++c) cv[c] = lv[c];
    }
  }
  if (cn != -1 && lane == 0) {
#pragma unroll
    for (int c = 0; c < NC; ++c) {
      if constexpr (PROD) atomicMulF(&out[(size_t)cn * NC + c], cv[c]);
      else atomicAdd(&out[(size_t)cn * NC + c], cv[c]);
    }
  }
}

// ---- node: marg = ehp*P/sum; hsum_new += deg*marg (block-reduced) ------
__global__ void node_post(const float* __restrict__ P, const float* __restrict__ deg,
                          const double* __restrict__ hsum_prev, double* __restrict__ hsum_new,
                          const float* __restrict__ beta_p, const double* __restrict__ two_m,
                          int N) {
  __shared__ float blk[4][4];
  int n = blockIdx.x * blockDim.x + threadIdx.x;
  float scale = -beta_p[0] / (float)two_m[0];
  float e0 = expf(scale * (float)hsum_prev[0]);
  float e1 = expf(scale * (float)hsum_prev[1]);
  float e2 = expf(scale * (float)hsum_prev[2]);
  float e3 = expf(scale * (float)hsum_prev[3]);
  float a0 = 0.f, a1 = 0.f, a2 = 0.f, a3 = 0.f;
  if (n < N) {
    float4 Pv = *reinterpret_cast<const float4*>(&P[(size_t)n * QD]);
    float m0 = e0 * Pv.x, m1 = e1 * Pv.y, m2 = e2 * Pv.z, m3 = e3 * Pv.w;
    float dinv = deg[n] / (m0 + m1 + m2 + m3);
    a0 = m0 * dinv; a1 = m1 * dinv; a2 = m2 * dinv; a3 = m3 * dinv;
  }
  a0 = wave_red(a0); a1 = wave_red(a1); a2 = wave_red(a2); a3 = wave_red(a3);
  int wid = threadIdx.x >> 6;
  if ((threadIdx.x & 63) == 0) {
    blk[wid][0] = a0; blk[wid][1] = a1; blk[wid][2] = a2; blk[wid][3] = a3;
  }
  __syncthreads();
  if (threadIdx.x < 4) {
    float s = blk[0][threadIdx.x] + blk[1][threadIdx.x] + blk[2][threadIdx.x] +
              blk[3][threadIdx.x];
    atomicAdd(&hsum_new[threadIdx.x], (double)s);
  }
}

__global__ void node_post_final(const float* __restrict__ P, const float* __restrict__ deg,
                                const double* __restrict__ hsum, const float* __restrict__ beta_p,
                                const double* __restrict__ two_m, float* __restrict__ out_s,
                                double* __restrict__ comm_raw, int N) {
  __shared__ float blk[4][4];
  int n = blockIdx.x * blockDim.x + threadIdx.x;
  float scale = -beta_p[0] / (float)two_m[0];
  float e0 = expf(scale * (float)hsum[0]);
  float e1 = expf(scale * (float)hsum[1]);
  float e2 = expf(scale * (float)hsum[2]);
  float e3 = expf(scale * (float)hsum[3]);
  float a0 = 0.f, a1 = 0.f, a2 = 0.f, a3 = 0.f;
  if (n < N) {
    float4 Pv = *reinterpret_cast<const float4*>(&P[(size_t)n * QD]);
    float m0 = e0 * Pv.x, m1 = e1 * Pv.y, m2 = e2 * Pv.z, m3 = e3 * Pv.w;
    float inv = 1.f / (m0 + m1 + m2 + m3);
    float4 s = make_float4(m0 * inv, m1 * inv, m2 * inv, m3 * inv);
    *reinterpret_cast<float4*>(&out_s[(size_t)n * QD]) = s;
    float d = deg[n];
    a0 = d * s.x; a1 = d * s.y; a2 = d * s.z; a3 = d * s.w;
  }
  a0 = wave_red(a0); a1 = wave_red(a1); a2 = wave_red(a2); a3 = wave_red(a3);
  int wid = threadIdx.x >> 6;
  if ((threadIdx.x & 63) == 0) {
    blk[wid][0] = a0; blk[wid][1] = a1; blk[wid][2] = a2; blk[wid][3] = a3;
  }
  __syncthreads();
  if (threadIdx.x < 4) {
    float s = blk[0][threadIdx.x] + blk[1][threadIdx.x] + blk[2][threadIdx.x] +
              blk[3][threadIdx.x];
    atomicAdd(&comm_raw[threadIdx.x], (double)s);
  }
}

// ---- cavity update, product form, zero transcendentals per edge --------
__global__ void edge_fuse(const int* __restrict__ ei, const float* __restrict__ em_buf,
                          const float* __restrict__ P, float* __restrict__ F,
                          const double* __restrict__ hsum, const float* __restrict__ beta_p,
                          const double* __restrict__ two_m, int E, int Eh) {
  int t = blockIdx.x * blockDim.x + threadIdx.x;
  if (t >= Eh) return;
  float scale = -beta_p[0] / (float)two_m[0];
  float e0 = expf(scale * (float)hsum[0]);
  float e1 = expf(scale * (float)hsum[1]);
  float e2 = expf(scale * (float)hsum[2]);
  float e3 = expf(scale * (float)hsum[3]);
  int s1 = ei[t];
  int d1 = ei[E + t];
  float em = em_buf[t];
  float4 F1 = *reinterpret_cast<const float4*>(&F[(size_t)t * QD]);
  float4 F2 = *reinterpret_cast<const float4*>(&F[((size_t)t + Eh) * QD]);
  float4 Ps = *reinterpret_cast<const float4*>(&P[(size_t)s1 * QD]);
  float4 Pd = *reinterpret_cast<const float4*>(&P[(size_t)d1 * QD]);
  // dir 1 (s1->d1): psi ∝ eh*Ps/F2  (multiply through by prod(F2))
  {
    float a01 = F2.x * F2.y, a23 = F2.z * F2.w;
    float x0 = F2.y * a23, x1 = F2.x * a23, x2 = a01 * F2.w, x3 = a01 * F2.z;
    float n0 = e0 * Ps.x * x0, n1 = e1 * Ps.y * x1;
    float n2 = e2 * Ps.z * x2, n3 = e3 * Ps.w * x3;
    float tt = em / (n0 + n1 + n2 + n3);
    float4 Fn = make_float4(fmaf(n0, tt, 1.f), fmaf(n1, tt, 1.f),
                            fmaf(n2, tt, 1.f), fmaf(n3, tt, 1.f));
    *reinterpret_cast<float4*>(&F[(size_t)t * QD]) = Fn;
  }
  // dir 2 (d1->s1): psi ∝ eh*Pd/F1
  {
    float a01 = F1.x * F1.y, a23 = F1.z * F1.w;
    float x0 = F1.y * a23, x1 = F1.x * a23, x2 = a01 * F1.w, x3 = a01 * F1.z;
    float n0 = e0 * Pd.x * x0, n1 = e1 * Pd.y * x1;
    float n2 = e2 * Pd.z * x2, n3 = e3 * Pd.w * x3;
    float tt = em / (n0 + n1 + n2 + n3);
    float4 Fn = make_float4(fmaf(n0, tt, 1.f), fmaf(n1, tt, 1.f),
                            fmaf(n2, tt, 1.f), fmaf(n3, tt, 1.f));
    *reinterpret_cast<float4*>(&F[((size_t)t + Eh) * QD]) = Fn;
  }
}

__global__ void edge_final(const int* __restrict__ ei, const float* __restrict__ w,
                           const float* __restrict__ out_s,
                           double* __restrict__ link_raw, int E, int Eh) {
  __shared__ float blk[4];
  int G = gridDim.x * blockDim.x;
  float c = 0.f;
  for (int t = blockIdx.x * blockDim.x + threadIdx.x; t < Eh; t += G) {
    int s1 = ei[t];
    int d1 = ei[E + t];
    float4 a = *reinterpret_cast<const float4*>(&out_s[(size_t)s1 * QD]);
    float4 b = *reinterpret_cast<const float4*>(&out_s[(size_t)d1 * QD]);
    float dot = a.x * b.x + a.y * b.y + a.z * b.z + a.w * b.w;
    c += 2.f * w[t] * dot;
  }
  c = wave_red(c);
  int wid = threadIdx.x >> 6;
  if ((threadIdx.x & 63) == 0) blk[wid] = c;
  __syncthreads();
  if (threadIdx.x == 0)
    atomicAdd(link_raw, (double)(blk[0] + blk[1] + blk[2] + blk[3]));
}

__global__ void finalize(const double* __restrict__ scal, float* __restrict__ out_q) {
  double tm = scal[0];
  double link = scal[1] / tm;
  double acc = 0.0;
#pragma unroll
  for (int k = 0; k < QD; ++k) {
    double c = scal[2 + k] / tm;
    acc += c * c;
  }
  out_q[0] = (float)(link - acc);
}

extern "C" void kernel_launch(void* const* d_in, const int* in_sizes, int n_in,
                              void* d_out, int out_size, void* d_ws, size_t ws_size,
                              hipStream_t stream) {
  const int* ei = (const int*)d_in[0];         // [2,E] int32
  const float* w = (const float*)d_in[1];      // [E]
  const float* msg = (const float*)d_in[2];    // [E,4]
  const float* beta_p = (const float*)d_in[3]; // scalar

  const int E = in_sizes[1];
  const int Eh = E / 2;
  const int N = (out_size - 1) / QD;

  // ws: scal [0]=two_m [1]=link [2..5]=comm [6+4i..]=hsum (i=0..10)
  char* p = (char*)d_ws;
  double* scal = (double*)p;
  size_t off = 512;
  int* cnt = (int*)(p + off); off += (size_t)N * 4;
  int* rowStart = (int*)(p + off); off += (size_t)(N + 1) * 4;
  off = (off + 127) & ~(size_t)127;
  int* bsum = (int*)(p + off); off += 1024;
  int* inc = (int*)(p + off); off += (size_t)E * 4;
  float* deg = (float*)(p + off); off += (size_t)N * 4;
  off = (off + 15) & ~(size_t)15;
  float* P = (float*)(p + off); off += (size_t)N * QD * 4;
  float* em = (float*)(p + off); off += (size_t)Eh * 4;
  off = (off + 15) & ~(size_t)15;
  float* F = (float*)(p + off); off += (size_t)E * QD * 4;
  int* rank = (int*)F;  // alias: rank dead before F is first written
  int* nodeOf = (int*)(p + off); off += (size_t)E * 4;
  (void)ws_size;

  double* hs = scal + 6;
  const int gEdir = (E + NBLK - 1) / NBLK;
  const int gE = (Eh + NBLK - 1) / NBLK;
  const int gN = (N + NBLK - 1) / NBLK;
  const int gH = (E + NBLK * 8 - 1) / (NBLK * 8);
  const int gSc = (E + NBLK * 4 - 1) / (NBLK * 4);
  const int gWp = (E + 2047) / 2048;   // gather_seg<4,PROD,8>: 2048 slots/block
  const int gWd = (E + 1023) / 1024;   // gather_seg<1,SUM,4>:  1024 slots/block
  const int gF = (4 * N + NBLK - 1) / NBLK;
  const int NBscan = (N + 1023) / 1024;

  hipMemsetAsync(scal, 0, 512, stream);
  hipMemsetAsync(cnt, 0, (size_t)N * 4, stream);
  hipMemsetAsync(deg, 0, (size_t)N * 4, stream);

  hist_rank<<<gH, NBLK, 0, stream>>>(ei, cnt, rank, E);
  scanA<<<NBscan, 256, 0, stream>>>(cnt, rowStart, bsum, N);
  scanB<<<1, 256, 0, stream>>>(bsum, NBscan);
  scanC<<<(N + NBLK) / NBLK, NBLK, 0, stream>>>(rowStart, bsum, N, E);
  scatter_inc<<<gSc, NBLK, 0, stream>>>(ei, rowStart, rank, inc, E);
  build_nodeOf<<<gN, NBLK, 0, stream>>>(rowStart, nodeOf, N);

  setup_pairs<<<gE, NBLK, 0, stream>>>(w, msg, beta_p, F, em, scal, Eh);
  gather_seg<1, false, 4><<<gWd, NBLK, 0, stream>>>(inc, nodeOf, w, deg, E);

  float* out_s = (float*)d_out;
  for (int i = 1; i <= 10; ++i) {
    fillP<<<gF, NBLK, 0, stream>>>(P, 4 * N);
    gather_seg<4, true, 8><<<gWp, NBLK, 0, stream>>>(inc, nodeOf, F, P, E);
    node_post<<<gN, NBLK, 0, stream>>>(P, deg, hs + 4 * (i - 1), hs + 4 * i,
                                       beta_p, scal, N);
    edge_fuse<<<gE, NBLK, 0, stream>>>(ei, em, P, F, hs + 4 * i, beta_p, scal, E, Eh);
  }
  fillP<<<gF, NBLK, 0, stream>>>(P, 4 * N);
  gather_seg<4, true, 8><<<gWp, NBLK, 0, stream>>>(inc, nodeOf, F, P, E);
  node_post_final<<<gN, NBLK, 0, stream>>>(P, deg, hs + 40, beta_p, scal,
                                           out_s, scal + 2, N);
  edge_final<<<512, NBLK, 0, stream>>>(ei, w, out_s, scal + 1, E, Eh);
  finalize<<<1, 1, 0, stream>>>(scal, out_s + (size_t)N * QD);
}